// Round 3
// baseline (5234.443 us; speedup 1.0000x reference)
//
#include <hip/hip_runtime.h>
#include <math.h>

// Problem constants
#define BB   8
#define NN   1024
#define DIN  768
#define DD   384
#define LL   6
#define HH   12
#define HDD  32
#define MM   (BB*NN)        // 8192 rows
#define EPSF 1e-5f

// ---------------------------------------------------------------------------
// Bool-mask normalization. The harness contract doesn't pin down how jnp bool
// arrays are uploaded (1-byte bool vs int32). Detect at runtime: read the
// first n/4 words as int32 (in-bounds under BOTH layouts: n bytes if packed,
// n elements if int32). Byte-packed bools yield words outside {0,1} with
// probability ~1 for these masks; int32 bools are exactly {0,1}.
// ---------------------------------------------------------------------------
__global__ __launch_bounds__(1024) void cvt_mask_k(const void* __restrict__ src,
                                                   int n, int* __restrict__ dst)
{
    __shared__ int flag;
    if (threadIdx.x == 0) flag = 0;
    __syncthreads();
    const int* si = (const int*)src;
    int nq = n >> 2;
    int any = 0;
    for (int i = threadIdx.x; i < nq; i += blockDim.x) any |= si[i] & ~1;
    if (any) atomicOr(&flag, 1);
    __syncthreads();
    if (flag) {                                   // 1-byte bool layout
        const unsigned char* sb = (const unsigned char*)src;
        for (int i = threadIdx.x; i < n; i += blockDim.x) dst[i] = sb[i];
    } else {                                      // int32 layout
        for (int i = threadIdx.x; i < n; i += blockDim.x) dst[i] = si[i];
    }
}

// ---------------------------------------------------------------------------
// GEMM: C[M x NO] = A[M x K] @ W[K x NO]  (+ epilogue)
// BM=128, BN=64, BK=16, 256 threads, 8x4 micro-tile per thread.
// All our shapes satisfy M%128==0, NO%64==0, K%16==0 -> no bounds checks.
// EPI: 0=bias  1=embed(bias,mask_token,pos-embeds)  2=residual h+=ls*(acc+b)  3=gelu
// ---------------------------------------------------------------------------
template <int EPI>
__global__ __launch_bounds__(256) void gemm_k(
    const float* __restrict__ A, const float* __restrict__ Wt,
    const float* __restrict__ bias, float* __restrict__ C,
    int K, int NO,
    const float* __restrict__ ls,
    const int* __restrict__ tmask, const int* __restrict__ hids,
    const int* __restrict__ wids, const float* __restrict__ mtok,
    const float* __restrict__ hemb, const float* __restrict__ wemb)
{
    __shared__ float As[16][132];   // transposed: As[k][row], +4 pad
    __shared__ float Bs[16][64];

    const int tid = threadIdx.x;
    const int tx = tid & 15;        // 16 col-threads  -> 4 cols each
    const int ty = tid >> 4;        // 16 row-threads  -> 8 rows each
    const int rowBase = blockIdx.x * 128;
    const int colBase = blockIdx.y * 64;

    float acc[8][4] = {};

    for (int k0 = 0; k0 < K; k0 += 16) {
        // --- stage A tile (128x16), 2 x float4 per thread, write transposed
        #pragma unroll
        for (int i = 0; i < 2; ++i) {
            int s   = tid + i * 256;       // 0..511 float4 slots
            int row = s >> 2;              // 0..127
            int kq  = (s & 3) * 4;         // 0,4,8,12
            float4 av = *(const float4*)(&A[(size_t)(rowBase + row) * K + k0 + kq]);
            As[kq + 0][row] = av.x;
            As[kq + 1][row] = av.y;
            As[kq + 2][row] = av.z;
            As[kq + 3][row] = av.w;
        }
        // --- stage B tile (16x64), 1 x float4 per thread
        {
            int r = tid >> 4;              // 0..15
            int c = (tid & 15) * 4;        // 0..60
            *(float4*)(&Bs[r][c]) =
                *(const float4*)(&Wt[(size_t)(k0 + r) * NO + colBase + c]);
        }
        __syncthreads();

        #pragma unroll
        for (int k = 0; k < 16; ++k) {
            float4 b4 = *(const float4*)(&Bs[k][tx * 4]);
            float4 a0 = *(const float4*)(&As[k][ty * 8]);
            float4 a1 = *(const float4*)(&As[k][ty * 8 + 4]);
            float a[8] = {a0.x, a0.y, a0.z, a0.w, a1.x, a1.y, a1.z, a1.w};
            float b[4] = {b4.x, b4.y, b4.z, b4.w};
            #pragma unroll
            for (int i = 0; i < 8; ++i)
                #pragma unroll
                for (int j = 0; j < 4; ++j)
                    acc[i][j] = fmaf(a[i], b[j], acc[i][j]);
        }
        __syncthreads();
    }

    // --- epilogue (float4 per row)
    const int cb = colBase + tx * 4;
    float4 bi = *(const float4*)(&bias[cb]);
    #pragma unroll
    for (int i = 0; i < 8; ++i) {
        int r = rowBase + ty * 8 + i;
        float v[4];
        #pragma unroll
        for (int j = 0; j < 4; ++j) v[j] = acc[i][j] + ((const float*)&bi)[j];

        float* cp = &C[(size_t)r * NO + cb];
        if constexpr (EPI == 1) {            // embed epilogue
            int tm = tmask[r];
            const float* he = &hemb[(size_t)hids[r] * DD + cb];
            const float* we = &wemb[(size_t)wids[r] * DD + cb];
            float4 o;
            #pragma unroll
            for (int j = 0; j < 4; ++j) {
                float x = tm ? mtok[cb + j] : v[j];
                ((float*)&o)[j] = x + he[j] + we[j];
            }
            *(float4*)cp = o;
        } else if constexpr (EPI == 2) {     // residual: h += ls*(acc+bias)
            float4 hv = *(const float4*)cp;
            float4 lv = *(const float4*)(&ls[cb]);
            float4 o;
            #pragma unroll
            for (int j = 0; j < 4; ++j)
                ((float*)&o)[j] = ((const float*)&hv)[j] +
                                  ((const float*)&lv)[j] * v[j];
            *(float4*)cp = o;
        } else if constexpr (EPI == 3) {     // exact gelu
            float4 o;
            #pragma unroll
            for (int j = 0; j < 4; ++j)
                ((float*)&o)[j] = 0.5f * v[j] * (1.0f + erff(v[j] * 0.70710678118654752f));
            *(float4*)cp = o;
        } else {
            float4 o = {v[0], v[1], v[2], v[3]};
            *(float4*)cp = o;
        }
    }
}

// ---------------------------------------------------------------------------
// LayerNorm: one wave per row (384 cols -> 6 per lane), 4 rows per block
// ---------------------------------------------------------------------------
__global__ __launch_bounds__(256) void ln_k(
    const float* __restrict__ X, const float* __restrict__ w,
    const float* __restrict__ b, float* __restrict__ Y)
{
    int row  = blockIdx.x * 4 + (threadIdx.x >> 6);
    int lane = threadIdx.x & 63;
    const float* xr = X + (size_t)row * DD;

    float x[6];
    #pragma unroll
    for (int j = 0; j < 6; ++j) x[j] = xr[lane + 64 * j];

    float s = 0.f;
    #pragma unroll
    for (int j = 0; j < 6; ++j) s += x[j];
    #pragma unroll
    for (int off = 32; off > 0; off >>= 1) s += __shfl_xor(s, off);
    float mu = s * (1.0f / 384.0f);

    float v = 0.f;
    #pragma unroll
    for (int j = 0; j < 6; ++j) { float d = x[j] - mu; v += d * d; }
    #pragma unroll
    for (int off = 32; off > 0; off >>= 1) v += __shfl_xor(v, off);
    float rstd = rsqrtf(v * (1.0f / 384.0f) + EPSF);

    float* yr = Y + (size_t)row * DD;
    #pragma unroll
    for (int j = 0; j < 6; ++j) {
        int c = lane + 64 * j;
        yr[c] = (x[j] - mu) * rstd * w[c] + b[c];
    }
}

// ---------------------------------------------------------------------------
// Flash-style attention. qkv layout: [M][3*D] with (3, H, HD) inner order.
// 1 thread = 1 query row; K/V staged in LDS in 128-key tiles.
// Mask on the fly: mask = (sid_q != sid_k) | sm_q | sm_k ; masked -> finfo.min
// out written as [B, N, D] rows (heads concatenated) -> feeds proj GEMM.
// ---------------------------------------------------------------------------
__global__ __launch_bounds__(128) void attn_k(
    const float* __restrict__ qkv, const int* __restrict__ sids,
    const int* __restrict__ smask, float* __restrict__ out)
{
    __shared__ float Ks[128][32];
    __shared__ float Vs[128][32];
    __shared__ int   sidk[128];
    __shared__ int   smk[128];

    const int tid = threadIdx.x;
    const int nqt = NN / 128;                  // 8 q-tiles per (b,h)
    int bh = blockIdx.x / nqt, qt = blockIdx.x % nqt;
    int b = bh / HH, h = bh % HH;
    int q = qt * 128 + tid;

    const size_t rq = (size_t)(b * NN + q) * (3 * DD) + h * HDD;
    float qreg[32];
    #pragma unroll
    for (int d4 = 0; d4 < 8; ++d4) {
        float4 t = *(const float4*)(&qkv[rq + d4 * 4]);
        qreg[d4 * 4 + 0] = t.x; qreg[d4 * 4 + 1] = t.y;
        qreg[d4 * 4 + 2] = t.z; qreg[d4 * 4 + 3] = t.w;
    }
    const int  sq  = sids[b * NN + q];
    const bool smq = smask[b * NN + q] != 0;

    float m = -INFINITY, l = 0.f, o[32] = {};
    const float scale = 0.17677669529663687f;  // HD^-0.5

    for (int kt = 0; kt < NN / 128; ++kt) {
        int k0 = kt * 128;
        size_t rk = (size_t)(b * NN + k0 + tid) * (3 * DD) + DD + h * HDD;
        #pragma unroll
        for (int d4 = 0; d4 < 8; ++d4)
            *(float4*)(&Ks[tid][d4 * 4]) = *(const float4*)(&qkv[rk + d4 * 4]);
        #pragma unroll
        for (int d4 = 0; d4 < 8; ++d4)
            *(float4*)(&Vs[tid][d4 * 4]) = *(const float4*)(&qkv[rk + DD + d4 * 4]);
        sidk[tid] = sids[b * NN + k0 + tid];
        smk[tid]  = smask[b * NN + k0 + tid];
        __syncthreads();

        for (int j = 0; j < 128; ++j) {
            float s = 0.f;
            #pragma unroll
            for (int d4 = 0; d4 < 8; ++d4) {
                float4 kv = *(const float4*)(&Ks[j][d4 * 4]);
                s = fmaf(qreg[d4 * 4 + 0], kv.x, s);
                s = fmaf(qreg[d4 * 4 + 1], kv.y, s);
                s = fmaf(qreg[d4 * 4 + 2], kv.z, s);
                s = fmaf(qreg[d4 * 4 + 3], kv.w, s);
            }
            s *= scale;
            if ((sq != sidk[j]) | smq | (smk[j] != 0)) s = -3.402823466e38f;
            if (s > m) {                        // rare after warmup
                float fac = __expf(m - s);
                m = s;
                l *= fac;
                #pragma unroll
                for (int d = 0; d < 32; ++d) o[d] *= fac;
            }
            float p = __expf(s - m);
            l += p;
            #pragma unroll
            for (int d4 = 0; d4 < 8; ++d4) {
                float4 vv = *(const float4*)(&Vs[j][d4 * 4]);
                o[d4 * 4 + 0] = fmaf(p, vv.x, o[d4 * 4 + 0]);
                o[d4 * 4 + 1] = fmaf(p, vv.y, o[d4 * 4 + 1]);
                o[d4 * 4 + 2] = fmaf(p, vv.z, o[d4 * 4 + 2]);
                o[d4 * 4 + 3] = fmaf(p, vv.w, o[d4 * 4 + 3]);
            }
        }
        __syncthreads();
    }

    float inv = 1.0f / l;
    float* op = &out[(size_t)(b * NN + q) * DD + h * HDD];
    #pragma unroll
    for (int d4 = 0; d4 < 8; ++d4) {
        float4 t = {o[d4 * 4 + 0] * inv, o[d4 * 4 + 1] * inv,
                    o[d4 * 4 + 2] * inv, o[d4 * 4 + 3] * inv};
        *(float4*)(&op[d4 * 4]) = t;
    }
}

// ---------------------------------------------------------------------------
extern "C" void kernel_launch(void* const* d_in, const int* in_sizes, int n_in,
                              void* d_out, int out_size, void* d_ws, size_t ws_size,
                              hipStream_t stream)
{
    const float* x        = (const float*)d_in[0];
    const int*   hids     = (const int*)d_in[1];
    const int*   wids     = (const int*)d_in[2];
    const void*  tmask_rw = d_in[3];               // bool (layout detected)
    const int*   sids     = (const int*)d_in[4];
    const void*  smask_rw = d_in[5];               // bool (layout detected)
    // d_in[6] = r (unused)
    const float* embed_w  = (const float*)d_in[7];
    const float* embed_b  = (const float*)d_in[8];
    const float* h_embed  = (const float*)d_in[9];
    const float* w_embed  = (const float*)d_in[10];
    const float* mtok     = (const float*)d_in[11];
    const float* norm1_w  = (const float*)d_in[12];
    const float* norm1_b  = (const float*)d_in[13];
    const float* ls1      = (const float*)d_in[14];
    const float* qkv_w    = (const float*)d_in[15];
    const float* qkv_b    = (const float*)d_in[16];
    const float* proj_w   = (const float*)d_in[17];
    const float* proj_b   = (const float*)d_in[18];
    const float* norm2_w  = (const float*)d_in[19];
    const float* norm2_b  = (const float*)d_in[20];
    const float* fc1_w    = (const float*)d_in[21];
    const float* fc1_b    = (const float*)d_in[22];
    const float* fc2_w    = (const float*)d_in[23];
    const float* fc2_b    = (const float*)d_in[24];
    const float* ls2      = (const float*)d_in[25];
    const float* pnorm_w  = (const float*)d_in[26];
    const float* pnorm_b  = (const float*)d_in[27];
    const float* pproj_w  = (const float*)d_in[28];
    const float* pproj_b  = (const float*)d_in[29];

    const size_t MD = (size_t)MM * DD;
    float* h    = (float*)d_ws;        // M x D
    float* z    = h   + MD;            // M x D   (ln out; REUSED for attn out)
    float* big  = z   + MD;            // M x 4D  (qkv / MLP hidden)
    int*   tm32 = (int*)(big + 4 * MD);// M
    int*   sm32 = tm32 + MM;           // M
    // total: 6*M*D*4 + 2*M*4 = 75.6 MB

    // normalize bool masks to int32 (layout auto-detected)
    cvt_mask_k<<<1, 1024, 0, stream>>>(tmask_rw, MM, tm32);
    cvt_mask_k<<<1, 1024, 0, stream>>>(smask_rw, MM, sm32);

    dim3 blk(256);
    #define GEMM(EPI, A_, W_, B_, C_, K_, NO_, LS_, TM_, HI_, WI_, MT_, HE_, WE_)   \
        gemm_k<EPI><<<dim3(MM/128, (NO_)/64), blk, 0, stream>>>(                    \
            A_, W_, B_, C_, K_, NO_, LS_, TM_, HI_, WI_, MT_, HE_, WE_)

    // embed + mask_token + pos embeds
    GEMM(1, x, embed_w, embed_b, h, DIN, DD, nullptr, tm32, hids, wids, mtok, h_embed, w_embed);

    for (int i = 0; i < LL; ++i) {
        ln_k<<<MM/4, blk, 0, stream>>>(h, norm1_w + i*DD, norm1_b + i*DD, z);
        GEMM(0, z, qkv_w + (size_t)i*DD*3*DD, qkv_b + i*3*DD, big, DD, 3*DD,
             nullptr, nullptr, nullptr, nullptr, nullptr, nullptr, nullptr);
        attn_k<<<BB*HH*(NN/128), dim3(128), 0, stream>>>(big, sids, sm32, z);
        GEMM(2, z, proj_w + (size_t)i*DD*DD, proj_b + i*DD, h, DD, DD,
             ls1 + i*DD, nullptr, nullptr, nullptr, nullptr, nullptr, nullptr);
        ln_k<<<MM/4, blk, 0, stream>>>(h, norm2_w + i*DD, norm2_b + i*DD, z);
        GEMM(3, z, fc1_w + (size_t)i*DD*4*DD, fc1_b + i*4*DD, big, DD, 4*DD,
             nullptr, nullptr, nullptr, nullptr, nullptr, nullptr, nullptr);
        GEMM(2, big, fc2_w + (size_t)i*4*DD*DD, fc2_b + i*DD, h, 4*DD, DD,
             ls2 + i*DD, nullptr, nullptr, nullptr, nullptr, nullptr, nullptr);
    }

    ln_k<<<MM/4, blk, 0, stream>>>(h, pnorm_w, pnorm_b, z);
    GEMM(0, z, pproj_w, pproj_b, (float*)d_out, DD, DIN,
         nullptr, nullptr, nullptr, nullptr, nullptr, nullptr, nullptr);
    #undef GEMM
}

// Round 6
// 3180.515 us; speedup vs baseline: 1.6458x; 1.6458x over previous
//
#include <hip/hip_runtime.h>
#include <math.h>

// Problem constants
#define BB   8
#define NN   1024
#define DIN  768
#define DD   384
#define LL   6
#define HH   12
#define HDD  32
#define MM   (BB*NN)        // 8192 rows
#define EPSF 1e-5f

typedef __attribute__((ext_vector_type(8))) short short8;   // 8 bf16 (4 VGPRs)
typedef __attribute__((ext_vector_type(4))) float f32x4;    // MFMA acc

__device__ __forceinline__ unsigned short f2b(float f) {    // RNE fp32->bf16
    unsigned int u = __builtin_bit_cast(unsigned int, f);
    u = (u + 0x7fffu + ((u >> 16) & 1u)) >> 16;
    return (unsigned short)u;
}
__device__ __forceinline__ float b2f(unsigned short h) {
    return __builtin_bit_cast(float, ((unsigned int)h) << 16);
}

// ---------------------------------------------------------------------------
// Bool-mask normalization (layout auto-detected; see round-2 note).
// ---------------------------------------------------------------------------
__global__ __launch_bounds__(1024) void cvt_mask_k(const void* __restrict__ src,
                                                   int n, int* __restrict__ dst)
{
    __shared__ int flag;
    if (threadIdx.x == 0) flag = 0;
    __syncthreads();
    const int* si = (const int*)src;
    int nq = n >> 2;
    int any = 0;
    for (int i = threadIdx.x; i < nq; i += blockDim.x) any |= si[i] & ~1;
    if (any) atomicOr(&flag, 1);
    __syncthreads();
    if (flag) {
        const unsigned char* sb = (const unsigned char*)src;
        for (int i = threadIdx.x; i < n; i += blockDim.x) dst[i] = sb[i];
    } else {
        for (int i = threadIdx.x; i < n; i += blockDim.x) dst[i] = si[i];
    }
}

// ---------------------------------------------------------------------------
// Weight transpose+cast: W fp32 [K][N] -> Wt bf16 [N][K]; one layer per blockIdx.z
// ---------------------------------------------------------------------------
__global__ __launch_bounds__(256) void tcast_k(const float* __restrict__ W,
                                               unsigned short* __restrict__ Wt,
                                               int K, int N)
{
    __shared__ float tile[32][33];
    const size_t lstr = (size_t)K * N;
    const float* Wl = W + blockIdx.z * lstr;
    unsigned short* Wtl = Wt + blockIdx.z * lstr;
    int k0 = blockIdx.x * 32, n0 = blockIdx.y * 32;
    int tx = threadIdx.x & 31, ty = threadIdx.x >> 5;      // ty 0..7
    #pragma unroll
    for (int r = 0; r < 32; r += 8)
        tile[ty + r][tx] = Wl[(size_t)(k0 + ty + r) * N + n0 + tx];
    __syncthreads();
    #pragma unroll
    for (int r = 0; r < 32; r += 8)
        Wtl[(size_t)(n0 + ty + r) * K + k0 + tx] = f2b(tile[tx][ty + r]);
}

// ---------------------------------------------------------------------------
// bf16 MFMA GEMM: C[M x NO] = A[M x K] @ W[K x NO]
//   A  : bf16 [M][K] row-major
//   Wt : bf16 [NO][K] row-major (pre-transposed weights)
// Tile 128x128, BK=32, 256 thr = 4 waves (2x2), 64x64 per wave = 4x4 frags of
// 16x16x32. LDS rows padded to 40 bf16 (80 B, 16B-aligned, bank-stride 20).
// EPI: 0 = bias -> bf16 out ; 2 = h += ls*(acc+bias) (fp32) ; 3 = gelu -> bf16
// ---------------------------------------------------------------------------
template <int EPI>
__global__ __launch_bounds__(256) void bgemm_k(
    const unsigned short* __restrict__ A, const unsigned short* __restrict__ Wt,
    const float* __restrict__ bias, void* __restrict__ out,
    int K, int NO, const float* __restrict__ ls)
{
    __shared__ unsigned short As[128][40];
    __shared__ unsigned short Bs[128][40];

    const int tid  = threadIdx.x;
    const int lane = tid & 63;
    const int wave = tid >> 6;
    const int wr = wave >> 1, wc = wave & 1;
    const int rowBase = blockIdx.x * 128;
    const int colBase = blockIdx.y * 128;
    const int rr = lane & 15;
    const int kr = (lane >> 4) * 8;

    f32x4 acc[4][4] = {};

    for (int k0 = 0; k0 < K; k0 += 32) {
        #pragma unroll
        for (int i = 0; i < 2; ++i) {
            int s   = tid + i * 256;       // 0..511
            int row = s >> 2;              // 0..127
            int seg = (s & 3) * 8;         // bf16 offset 0,8,16,24
            *(short8*)&As[row][seg] =
                *(const short8*)&A[(size_t)(rowBase + row) * K + k0 + seg];
            *(short8*)&Bs[row][seg] =
                *(const short8*)&Wt[(size_t)(colBase + row) * K + k0 + seg];
        }
        __syncthreads();

        short8 af[4], bfr[4];
        #pragma unroll
        for (int i = 0; i < 4; ++i)
            af[i] = *(const short8*)&As[wr * 64 + i * 16 + rr][kr];
        #pragma unroll
        for (int j = 0; j < 4; ++j)
            bfr[j] = *(const short8*)&Bs[wc * 64 + j * 16 + rr][kr];
        #pragma unroll
        for (int i = 0; i < 4; ++i)
            #pragma unroll
            for (int j = 0; j < 4; ++j)
                acc[i][j] = __builtin_amdgcn_mfma_f32_16x16x32_bf16(
                    af[i], bfr[j], acc[i][j], 0, 0, 0);
        __syncthreads();
    }

    // epilogue: D element (row=(lane>>4)*4+r, col=lane&15) per 16x16 frag [m89]
    const int colq = colBase + wc * 64 + rr;
    const int rq0  = rowBase + wr * 64 + (lane >> 4) * 4;
    #pragma unroll
    for (int j = 0; j < 4; ++j) {
        const int col = colq + j * 16;
        const float bi = bias[col];
        float lsv = 0.f;
        if constexpr (EPI == 2) lsv = ls[col];
        #pragma unroll
        for (int i = 0; i < 4; ++i) {
            #pragma unroll
            for (int r = 0; r < 4; ++r) {
                const int row = rq0 + i * 16 + r;
                float v = acc[i][j][r] + bi;
                if constexpr (EPI == 0) {
                    ((unsigned short*)out)[(size_t)row * NO + col] = f2b(v);
                } else if constexpr (EPI == 2) {
                    float* hp = (float*)out + (size_t)row * NO + col;
                    *hp += lsv * v;
                } else {  // gelu (exact) -> bf16
                    float g = 0.5f * v * (1.0f + erff(v * 0.70710678118654752f));
                    ((unsigned short*)out)[(size_t)row * NO + col] = f2b(g);
                }
            }
        }
    }
}

// ---------------------------------------------------------------------------
// fp32 GEMM (embed + pproj only — full-scale precision paths stay fp32)
// EPI: 0=bias  1=embed(bias,mask_token,pos-embeds)
// ---------------------------------------------------------------------------
template <int EPI>
__global__ __launch_bounds__(256) void gemm_k(
    const float* __restrict__ A, const float* __restrict__ Wt,
    const float* __restrict__ bias, float* __restrict__ C,
    int K, int NO,
    const int* __restrict__ tmask, const int* __restrict__ hids,
    const int* __restrict__ wids, const float* __restrict__ mtok,
    const float* __restrict__ hemb, const float* __restrict__ wemb)
{
    __shared__ float As[16][132];
    __shared__ float Bs[16][64];

    const int tid = threadIdx.x;
    const int tx = tid & 15;
    const int ty = tid >> 4;
    const int rowBase = blockIdx.x * 128;
    const int colBase = blockIdx.y * 64;

    float acc[8][4] = {};

    for (int k0 = 0; k0 < K; k0 += 16) {
        #pragma unroll
        for (int i = 0; i < 2; ++i) {
            int s   = tid + i * 256;
            int row = s >> 2;
            int kq  = (s & 3) * 4;
            float4 av = *(const float4*)(&A[(size_t)(rowBase + row) * K + k0 + kq]);
            As[kq + 0][row] = av.x;
            As[kq + 1][row] = av.y;
            As[kq + 2][row] = av.z;
            As[kq + 3][row] = av.w;
        }
        {
            int r = tid >> 4;
            int c = (tid & 15) * 4;
            *(float4*)(&Bs[r][c]) =
                *(const float4*)(&Wt[(size_t)(k0 + r) * NO + colBase + c]);
        }
        __syncthreads();

        #pragma unroll
        for (int k = 0; k < 16; ++k) {
            float4 b4 = *(const float4*)(&Bs[k][tx * 4]);
            float4 a0 = *(const float4*)(&As[k][ty * 8]);
            float4 a1 = *(const float4*)(&As[k][ty * 8 + 4]);
            float a[8] = {a0.x, a0.y, a0.z, a0.w, a1.x, a1.y, a1.z, a1.w};
            float b[4] = {b4.x, b4.y, b4.z, b4.w};
            #pragma unroll
            for (int i = 0; i < 8; ++i)
                #pragma unroll
                for (int j = 0; j < 4; ++j)
                    acc[i][j] = fmaf(a[i], b[j], acc[i][j]);
        }
        __syncthreads();
    }

    const int cb = colBase + tx * 4;
    float4 bi = *(const float4*)(&bias[cb]);
    #pragma unroll
    for (int i = 0; i < 8; ++i) {
        int r = rowBase + ty * 8 + i;
        float v[4];
        #pragma unroll
        for (int j = 0; j < 4; ++j) v[j] = acc[i][j] + ((const float*)&bi)[j];

        float* cp = &C[(size_t)r * NO + cb];
        if constexpr (EPI == 1) {
            int tm = tmask[r];
            const float* he = &hemb[(size_t)hids[r] * DD + cb];
            const float* we = &wemb[(size_t)wids[r] * DD + cb];
            float4 o;
            #pragma unroll
            for (int j = 0; j < 4; ++j) {
                float x = tm ? mtok[cb + j] : v[j];
                ((float*)&o)[j] = x + he[j] + we[j];
            }
            *(float4*)cp = o;
        } else {
            float4 o = {v[0], v[1], v[2], v[3]};
            *(float4*)cp = o;
        }
    }
}

// ---------------------------------------------------------------------------
// LayerNorm: one wave per row. OUT: 0 = fp32, 1 = bf16
// ---------------------------------------------------------------------------
template <int OUT>
__global__ __launch_bounds__(256) void ln_k(
    const float* __restrict__ X, const float* __restrict__ w,
    const float* __restrict__ b, void* __restrict__ Y)
{
    int row  = blockIdx.x * 4 + (threadIdx.x >> 6);
    int lane = threadIdx.x & 63;
    const float* xr = X + (size_t)row * DD;

    float x[6];
    #pragma unroll
    for (int j = 0; j < 6; ++j) x[j] = xr[lane + 64 * j];

    float s = 0.f;
    #pragma unroll
    for (int j = 0; j < 6; ++j) s += x[j];
    #pragma unroll
    for (int off = 32; off > 0; off >>= 1) s += __shfl_xor(s, off);
    float mu = s * (1.0f / 384.0f);

    float v = 0.f;
    #pragma unroll
    for (int j = 0; j < 6; ++j) { float d = x[j] - mu; v += d * d; }
    #pragma unroll
    for (int off = 32; off > 0; off >>= 1) v += __shfl_xor(v, off);
    float rstd = rsqrtf(v * (1.0f / 384.0f) + EPSF);

    #pragma unroll
    for (int j = 0; j < 6; ++j) {
        int c = lane + 64 * j;
        float y = (x[j] - mu) * rstd * w[c] + b[c];
        if constexpr (OUT == 0) ((float*)Y)[(size_t)row * DD + c] = y;
        else ((unsigned short*)Y)[(size_t)row * DD + c] = f2b(y);
    }
}

// ---------------------------------------------------------------------------
// Flash-style attention, fp32 math, bf16 qkv in / bf16 out.
// LDS rows padded to 36 floats (kills the 16x staging write conflict).
// ---------------------------------------------------------------------------
__global__ __launch_bounds__(128) void attn_k(
    const unsigned short* __restrict__ qkv, const int* __restrict__ sids,
    const int* __restrict__ smask, unsigned short* __restrict__ out)
{
    __shared__ float Ks[128][36];
    __shared__ float Vs[128][36];
    __shared__ int   sidk[128];
    __shared__ int   smk[128];

    const int tid = threadIdx.x;
    const int nqt = NN / 128;
    int bh = blockIdx.x / nqt, qt = blockIdx.x % nqt;
    int b = bh / HH, h = bh % HH;
    int q = qt * 128 + tid;

    const size_t rq = (size_t)(b * NN + q) * (3 * DD) + h * HDD;
    float qreg[32];
    #pragma unroll
    for (int c = 0; c < 4; ++c) {
        short8 t = *(const short8*)&qkv[rq + c * 8];
        #pragma unroll
        for (int e = 0; e < 8; ++e) qreg[c * 8 + e] = b2f((unsigned short)t[e]);
    }
    const int  sq  = sids[b * NN + q];
    const bool smq = smask[b * NN + q] != 0;

    float m = -INFINITY, l = 0.f, o[32] = {};
    const float scale = 0.17677669529663687f;  // HD^-0.5

    for (int kt = 0; kt < NN / 128; ++kt) {
        int k0 = kt * 128;
        size_t rk = (size_t)(b * NN + k0 + tid) * (3 * DD) + DD + h * HDD;
        {
            short8 sh[4], sv[4];
            #pragma unroll
            for (int c = 0; c < 4; ++c) {
                sh[c] = *(const short8*)&qkv[rk + c * 8];
                sv[c] = *(const short8*)&qkv[rk + DD + c * 8];
            }
            #pragma unroll
            for (int d4 = 0; d4 < 8; ++d4) {
                float4 fk, fv;
                ((float*)&fk)[0] = b2f((unsigned short)sh[d4 >> 1][(d4 & 1) * 4 + 0]);
                ((float*)&fk)[1] = b2f((unsigned short)sh[d4 >> 1][(d4 & 1) * 4 + 1]);
                ((float*)&fk)[2] = b2f((unsigned short)sh[d4 >> 1][(d4 & 1) * 4 + 2]);
                ((float*)&fk)[3] = b2f((unsigned short)sh[d4 >> 1][(d4 & 1) * 4 + 3]);
                ((float*)&fv)[0] = b2f((unsigned short)sv[d4 >> 1][(d4 & 1) * 4 + 0]);
                ((float*)&fv)[1] = b2f((unsigned short)sv[d4 >> 1][(d4 & 1) * 4 + 1]);
                ((float*)&fv)[2] = b2f((unsigned short)sv[d4 >> 1][(d4 & 1) * 4 + 2]);
                ((float*)&fv)[3] = b2f((unsigned short)sv[d4 >> 1][(d4 & 1) * 4 + 3]);
                *(float4*)&Ks[tid][d4 * 4] = fk;
                *(float4*)&Vs[tid][d4 * 4] = fv;
            }
        }
        sidk[tid] = sids[b * NN + k0 + tid];
        smk[tid]  = smask[b * NN + k0 + tid];
        __syncthreads();

        for (int j = 0; j < 128; ++j) {
            float s = 0.f;
            #pragma unroll
            for (int d4 = 0; d4 < 8; ++d4) {
                float4 kv = *(const float4*)(&Ks[j][d4 * 4]);
                s = fmaf(qreg[d4 * 4 + 0], kv.x, s);
                s = fmaf(qreg[d4 * 4 + 1], kv.y, s);
                s = fmaf(qreg[d4 * 4 + 2], kv.z, s);
                s = fmaf(qreg[d4 * 4 + 3], kv.w, s);
            }
            s *= scale;
            if ((sq != sidk[j]) | smq | (smk[j] != 0)) s = -3.402823466e38f;
            if (s > m) {
                float fac = __expf(m - s);
                m = s;
                l *= fac;
                #pragma unroll
                for (int d = 0; d < 32; ++d) o[d] *= fac;
            }
            float p = __expf(s - m);
            l += p;
            #pragma unroll
            for (int d4 = 0; d4 < 8; ++d4) {
                float4 vv = *(const float4*)(&Vs[j][d4 * 4]);
                o[d4 * 4 + 0] = fmaf(p, vv.x, o[d4 * 4 + 0]);
                o[d4 * 4 + 1] = fmaf(p, vv.y, o[d4 * 4 + 1]);
                o[d4 * 4 + 2] = fmaf(p, vv.z, o[d4 * 4 + 2]);
                o[d4 * 4 + 3] = fmaf(p, vv.w, o[d4 * 4 + 3]);
            }
        }
        __syncthreads();
    }

    float inv = 1.0f / l;
    unsigned short* op = &out[(size_t)(b * NN + q) * DD + h * HDD];
    #pragma unroll
    for (int d4 = 0; d4 < 8; ++d4) {
        ushort4 t;
        t.x = f2b(o[d4 * 4 + 0] * inv);
        t.y = f2b(o[d4 * 4 + 1] * inv);
        t.z = f2b(o[d4 * 4 + 2] * inv);
        t.w = f2b(o[d4 * 4 + 3] * inv);
        *(ushort4*)&op[d4 * 4] = t;
    }
}

// ---------------------------------------------------------------------------
extern "C" void kernel_launch(void* const* d_in, const int* in_sizes, int n_in,
                              void* d_out, int out_size, void* d_ws, size_t ws_size,
                              hipStream_t stream)
{
    const float* x        = (const float*)d_in[0];
    const int*   hids     = (const int*)d_in[1];
    const int*   wids     = (const int*)d_in[2];
    const void*  tmask_rw = d_in[3];
    const int*   sids     = (const int*)d_in[4];
    const void*  smask_rw = d_in[5];
    const float* embed_w  = (const float*)d_in[7];
    const float* embed_b  = (const float*)d_in[8];
    const float* h_embed  = (const float*)d_in[9];
    const float* w_embed  = (const float*)d_in[10];
    const float* mtok     = (const float*)d_in[11];
    const float* norm1_w  = (const float*)d_in[12];
    const float* norm1_b  = (const float*)d_in[13];
    const float* ls1      = (const float*)d_in[14];
    const float* qkv_w    = (const float*)d_in[15];
    const float* qkv_b    = (const float*)d_in[16];
    const float* proj_w   = (const float*)d_in[17];
    const float* proj_b   = (const float*)d_in[18];
    const float* norm2_w  = (const float*)d_in[19];
    const float* norm2_b  = (const float*)d_in[20];
    const float* fc1_w    = (const float*)d_in[21];
    const float* fc1_b    = (const float*)d_in[22];
    const float* fc2_w    = (const float*)d_in[23];
    const float* fc2_b    = (const float*)d_in[24];
    const float* ls2      = (const float*)d_in[25];
    const float* pnorm_w  = (const float*)d_in[26];
    const float* pnorm_b  = (const float*)d_in[27];
    const float* pproj_w  = (const float*)d_in[28];
    const float* pproj_b  = (const float*)d_in[29];

    const size_t MD = (size_t)MM * DD;
    // Workspace layout (aliasing by liveness; all sequential on one stream):
    //   h    : fp32 MD                                (12.6 MB)
    //   zb   : bf16 MD   (ln1/ln2 out; also attn out) ( 6.3 MB)
    //   hid  : bf16 4*MD (mlp hidden; also qkv bf16; also fp32 pnorm out) (25.2 MB)
    //   wT   : bf16 6*(3DD*DD + DD*DD + 4DD*DD + 4DD*DD)                  (21.2 MB)
    //   tm32/sm32 : int MM each
    float*          h    = (float*)d_ws;
    unsigned short* zb   = (unsigned short*)(h + MD);
    unsigned short* hid  = zb + MD;                 // 4*MD ushorts
    unsigned short* qkvb = hid;                     // alias: 3*MD ushorts (disjoint liveness)
    float*          zf   = (float*)hid;            // alias: MD floats (pnorm out)
    unsigned short* wT   = hid + 4 * MD;
    const size_t qkvTsz = (size_t)LL * 3 * DD * DD;
    const size_t projTsz = (size_t)LL * DD * DD;
    const size_t fc1Tsz = (size_t)LL * DD * 4 * DD;
    unsigned short* qkvT = wT;
    unsigned short* projT = qkvT + qkvTsz;
    unsigned short* fc1T  = projT + projTsz;
    unsigned short* fc2T  = fc1T + fc1Tsz;
    int* tm32 = (int*)(fc2T + fc1Tsz);
    int* sm32 = tm32 + MM;

    cvt_mask_k<<<1, 1024, 0, stream>>>(tmask_rw, MM, tm32);
    cvt_mask_k<<<1, 1024, 0, stream>>>(smask_rw, MM, sm32);

    dim3 t256(256);
    // weights -> bf16 [N][K]
    tcast_k<<<dim3(DD/32, 3*DD/32, LL), t256, 0, stream>>>(qkv_w, qkvT, DD, 3*DD);
    tcast_k<<<dim3(DD/32, DD/32,   LL), t256, 0, stream>>>(proj_w, projT, DD, DD);
    tcast_k<<<dim3(DD/32, 4*DD/32, LL), t256, 0, stream>>>(fc1_w, fc1T, DD, 4*DD);
    tcast_k<<<dim3(4*DD/32, DD/32, LL), t256, 0, stream>>>(fc2_w, fc2T, 4*DD, DD);

    // embed + mask_token + pos embeds (fp32, full-scale path)
    gemm_k<1><<<dim3(MM/128, DD/64), t256, 0, stream>>>(
        x, embed_w, embed_b, h, DIN, DD, tm32, hids, wids, mtok, h_embed, w_embed);

    for (int i = 0; i < LL; ++i) {
        ln_k<1><<<MM/4, t256, 0, stream>>>(h, norm1_w + i*DD, norm1_b + i*DD, zb);
        bgemm_k<0><<<dim3(MM/128, 3*DD/128), t256, 0, stream>>>(
            zb, qkvT + (size_t)i*3*DD*DD, qkv_b + i*3*DD, qkvb, DD, 3*DD, nullptr);
        attn_k<<<BB*HH*(NN/128), dim3(128), 0, stream>>>(qkvb, sids, sm32, zb);
        bgemm_k<2><<<dim3(MM/128, DD/128), t256, 0, stream>>>(
            zb, projT + (size_t)i*DD*DD, proj_b + i*DD, h, DD, DD, ls1 + i*DD);
        ln_k<1><<<MM/4, t256, 0, stream>>>(h, norm2_w + i*DD, norm2_b + i*DD, zb);
        bgemm_k<3><<<dim3(MM/128, 4*DD/128), t256, 0, stream>>>(
            zb, fc1T + (size_t)i*DD*4*DD, fc1_b + i*4*DD, hid, DD, 4*DD, nullptr);
        bgemm_k<2><<<dim3(MM/128, DD/128), t256, 0, stream>>>(
            hid, fc2T + (size_t)i*4*DD*DD, fc2_b + i*DD, h, 4*DD, DD, ls2 + i*DD);
    }

    ln_k<0><<<MM/4, t256, 0, stream>>>(h, pnorm_w, pnorm_b, zf);
    gemm_k<0><<<dim3(MM/128, DIN/64), t256, 0, stream>>>(
        zf, pproj_w, pproj_b, (float*)d_out, DD, DIN,
        nullptr, nullptr, nullptr, nullptr, nullptr, nullptr);
}

// Round 7
// 1665.767 us; speedup vs baseline: 3.1424x; 1.9093x over previous
//
#include <hip/hip_runtime.h>
#include <math.h>

// Problem constants
#define BB   8
#define NN   1024
#define DIN  768
#define DD   384
#define LL   6
#define HH   12
#define HDD  32
#define MM   (BB*NN)        // 8192 rows
#define EPSF 1e-5f

typedef __attribute__((ext_vector_type(8))) short short8;   // 8 bf16 (4 VGPRs)
typedef __attribute__((ext_vector_type(4))) float f32x4;    // MFMA acc

__device__ __forceinline__ unsigned short f2b(float f) {    // RNE fp32->bf16
    unsigned int u = __builtin_bit_cast(unsigned int, f);
    u = (u + 0x7fffu + ((u >> 16) & 1u)) >> 16;
    return (unsigned short)u;
}
__device__ __forceinline__ float b2f(unsigned short h) {
    return __builtin_bit_cast(float, ((unsigned int)h) << 16);
}

// ---------------------------------------------------------------------------
// Bool-mask normalization (layout auto-detected; see round-2 note).
// ---------------------------------------------------------------------------
__global__ __launch_bounds__(1024) void cvt_mask_k(const void* __restrict__ src,
                                                   int n, int* __restrict__ dst)
{
    __shared__ int flag;
    if (threadIdx.x == 0) flag = 0;
    __syncthreads();
    const int* si = (const int*)src;
    int nq = n >> 2;
    int any = 0;
    for (int i = threadIdx.x; i < nq; i += blockDim.x) any |= si[i] & ~1;
    if (any) atomicOr(&flag, 1);
    __syncthreads();
    if (flag) {
        const unsigned char* sb = (const unsigned char*)src;
        for (int i = threadIdx.x; i < n; i += blockDim.x) dst[i] = sb[i];
    } else {
        for (int i = threadIdx.x; i < n; i += blockDim.x) dst[i] = si[i];
    }
}

// ---------------------------------------------------------------------------
// Weight transpose+cast: W fp32 [K][N] -> Wt bf16 [N][K]; one layer per blockIdx.z
// ---------------------------------------------------------------------------
__global__ __launch_bounds__(256) void tcast_k(const float* __restrict__ W,
                                               unsigned short* __restrict__ Wt,
                                               int K, int N)
{
    __shared__ float tile[32][33];
    const size_t lstr = (size_t)K * N;
    const float* Wl = W + blockIdx.z * lstr;
    unsigned short* Wtl = Wt + blockIdx.z * lstr;
    int k0 = blockIdx.x * 32, n0 = blockIdx.y * 32;
    int tx = threadIdx.x & 31, ty = threadIdx.x >> 5;      // ty 0..7
    #pragma unroll
    for (int r = 0; r < 32; r += 8)
        tile[ty + r][tx] = Wl[(size_t)(k0 + ty + r) * N + n0 + tx];
    __syncthreads();
    #pragma unroll
    for (int r = 0; r < 32; r += 8)
        Wtl[(size_t)(n0 + ty + r) * K + k0 + tx] = f2b(tile[tx][ty + r]);
}

// ---------------------------------------------------------------------------
// bf16 MFMA GEMM: C[M x NO] = A[M x K] @ W[K x NO]
//   A  : bf16 [M][K] row-major ; Wt : bf16 [NO][K] (pre-transposed weights)
// Tile 128x128, BK=32, 4 waves (2x2), 64x64/wave = 4x4 frags of 16x16x32.
// EPI: 0 = bias -> bf16 out ; 2 = h += ls*(acc+bias) (fp32) ; 3 = gelu -> bf16
// ---------------------------------------------------------------------------
template <int EPI>
__global__ __launch_bounds__(256) void bgemm_k(
    const unsigned short* __restrict__ A, const unsigned short* __restrict__ Wt,
    const float* __restrict__ bias, void* __restrict__ out,
    int K, int NO, const float* __restrict__ ls)
{
    __shared__ unsigned short As[128][40];
    __shared__ unsigned short Bs[128][40];

    const int tid  = threadIdx.x;
    const int lane = tid & 63;
    const int wave = tid >> 6;
    const int wr = wave >> 1, wc = wave & 1;
    const int rowBase = blockIdx.x * 128;
    const int colBase = blockIdx.y * 128;
    const int rr = lane & 15;
    const int kr = (lane >> 4) * 8;

    f32x4 acc[4][4] = {};

    for (int k0 = 0; k0 < K; k0 += 32) {
        #pragma unroll
        for (int i = 0; i < 2; ++i) {
            int s   = tid + i * 256;       // 0..511
            int row = s >> 2;              // 0..127
            int seg = (s & 3) * 8;         // bf16 offset 0,8,16,24
            *(short8*)&As[row][seg] =
                *(const short8*)&A[(size_t)(rowBase + row) * K + k0 + seg];
            *(short8*)&Bs[row][seg] =
                *(const short8*)&Wt[(size_t)(colBase + row) * K + k0 + seg];
        }
        __syncthreads();

        short8 af[4], bfr[4];
        #pragma unroll
        for (int i = 0; i < 4; ++i)
            af[i] = *(const short8*)&As[wr * 64 + i * 16 + rr][kr];
        #pragma unroll
        for (int j = 0; j < 4; ++j)
            bfr[j] = *(const short8*)&Bs[wc * 64 + j * 16 + rr][kr];
        #pragma unroll
        for (int i = 0; i < 4; ++i)
            #pragma unroll
            for (int j = 0; j < 4; ++j)
                acc[i][j] = __builtin_amdgcn_mfma_f32_16x16x32_bf16(
                    af[i], bfr[j], acc[i][j], 0, 0, 0);
        __syncthreads();
    }

    // epilogue: D element (row=(lane>>4)*4+r, col=lane&15) per 16x16 frag [m89]
    const int colq = colBase + wc * 64 + rr;
    const int rq0  = rowBase + wr * 64 + (lane >> 4) * 4;
    #pragma unroll
    for (int j = 0; j < 4; ++j) {
        const int col = colq + j * 16;
        const float bi = bias[col];
        float lsv = 0.f;
        if constexpr (EPI == 2) lsv = ls[col];
        #pragma unroll
        for (int i = 0; i < 4; ++i) {
            #pragma unroll
            for (int r = 0; r < 4; ++r) {
                const int row = rq0 + i * 16 + r;
                float v = acc[i][j][r] + bi;
                if constexpr (EPI == 0) {
                    ((unsigned short*)out)[(size_t)row * NO + col] = f2b(v);
                } else if constexpr (EPI == 2) {
                    float* hp = (float*)out + (size_t)row * NO + col;
                    *hp += lsv * v;
                } else {  // gelu (exact) -> bf16
                    float g = 0.5f * v * (1.0f + erff(v * 0.70710678118654752f));
                    ((unsigned short*)out)[(size_t)row * NO + col] = f2b(g);
                }
            }
        }
    }
}

// ---------------------------------------------------------------------------
// fp32 GEMM (embed + pproj only — full-scale precision paths stay fp32)
// EPI: 0=bias  1=embed(bias,mask_token,pos-embeds)
// ---------------------------------------------------------------------------
template <int EPI>
__global__ __launch_bounds__(256) void gemm_k(
    const float* __restrict__ A, const float* __restrict__ Wt,
    const float* __restrict__ bias, float* __restrict__ C,
    int K, int NO,
    const int* __restrict__ tmask, const int* __restrict__ hids,
    const int* __restrict__ wids, const float* __restrict__ mtok,
    const float* __restrict__ hemb, const float* __restrict__ wemb)
{
    __shared__ float As[16][132];
    __shared__ float Bs[16][64];

    const int tid = threadIdx.x;
    const int tx = tid & 15;
    const int ty = tid >> 4;
    const int rowBase = blockIdx.x * 128;
    const int colBase = blockIdx.y * 64;

    float acc[8][4] = {};

    for (int k0 = 0; k0 < K; k0 += 16) {
        #pragma unroll
        for (int i = 0; i < 2; ++i) {
            int s   = tid + i * 256;
            int row = s >> 2;
            int kq  = (s & 3) * 4;
            float4 av = *(const float4*)(&A[(size_t)(rowBase + row) * K + k0 + kq]);
            As[kq + 0][row] = av.x;
            As[kq + 1][row] = av.y;
            As[kq + 2][row] = av.z;
            As[kq + 3][row] = av.w;
        }
        {
            int r = tid >> 4;
            int c = (tid & 15) * 4;
            *(float4*)(&Bs[r][c]) =
                *(const float4*)(&Wt[(size_t)(k0 + r) * NO + colBase + c]);
        }
        __syncthreads();

        #pragma unroll
        for (int k = 0; k < 16; ++k) {
            float4 b4 = *(const float4*)(&Bs[k][tx * 4]);
            float4 a0 = *(const float4*)(&As[k][ty * 8]);
            float4 a1 = *(const float4*)(&As[k][ty * 8 + 4]);
            float a[8] = {a0.x, a0.y, a0.z, a0.w, a1.x, a1.y, a1.z, a1.w};
            float b[4] = {b4.x, b4.y, b4.z, b4.w};
            #pragma unroll
            for (int i = 0; i < 8; ++i)
                #pragma unroll
                for (int j = 0; j < 4; ++j)
                    acc[i][j] = fmaf(a[i], b[j], acc[i][j]);
        }
        __syncthreads();
    }

    const int cb = colBase + tx * 4;
    float4 bi = *(const float4*)(&bias[cb]);
    #pragma unroll
    for (int i = 0; i < 8; ++i) {
        int r = rowBase + ty * 8 + i;
        float v[4];
        #pragma unroll
        for (int j = 0; j < 4; ++j) v[j] = acc[i][j] + ((const float*)&bi)[j];

        float* cp = &C[(size_t)r * NO + cb];
        if constexpr (EPI == 1) {
            int tm = tmask[r];
            const float* he = &hemb[(size_t)hids[r] * DD + cb];
            const float* we = &wemb[(size_t)wids[r] * DD + cb];
            float4 o;
            #pragma unroll
            for (int j = 0; j < 4; ++j) {
                float x = tm ? mtok[cb + j] : v[j];
                ((float*)&o)[j] = x + he[j] + we[j];
            }
            *(float4*)cp = o;
        } else {
            float4 o = {v[0], v[1], v[2], v[3]};
            *(float4*)cp = o;
        }
    }
}

// ---------------------------------------------------------------------------
// LayerNorm: one wave per row. OUT: 0 = fp32, 1 = bf16
// ---------------------------------------------------------------------------
template <int OUT>
__global__ __launch_bounds__(256) void ln_k(
    const float* __restrict__ X, const float* __restrict__ w,
    const float* __restrict__ b, void* __restrict__ Y)
{
    int row  = blockIdx.x * 4 + (threadIdx.x >> 6);
    int lane = threadIdx.x & 63;
    const float* xr = X + (size_t)row * DD;

    float x[6];
    #pragma unroll
    for (int j = 0; j < 6; ++j) x[j] = xr[lane + 64 * j];

    float s = 0.f;
    #pragma unroll
    for (int j = 0; j < 6; ++j) s += x[j];
    #pragma unroll
    for (int off = 32; off > 0; off >>= 1) s += __shfl_xor(s, off);
    float mu = s * (1.0f / 384.0f);

    float v = 0.f;
    #pragma unroll
    for (int j = 0; j < 6; ++j) { float d = x[j] - mu; v += d * d; }
    #pragma unroll
    for (int off = 32; off > 0; off >>= 1) v += __shfl_xor(v, off);
    float rstd = rsqrtf(v * (1.0f / 384.0f) + EPSF);

    #pragma unroll
    for (int j = 0; j < 6; ++j) {
        int c = lane + 64 * j;
        float y = (x[j] - mu) * rstd * w[c] + b[c];
        if constexpr (OUT == 0) ((float*)Y)[(size_t)row * DD + c] = y;
        else ((unsigned short*)Y)[(size_t)row * DD + c] = f2b(y);
    }
}

// ---------------------------------------------------------------------------
// MFMA flash attention.  HD=32 == K-dim of mfma_f32_16x16x32_bf16.
// Block = 256 thr = 4 waves; wave owns 16 queries; block = 64 queries of (b,h).
// Key loop: KT=64 keys/tile.
//   S-tile : A-frag = Q (global 16B loads), B-frag = K rows (global 16B loads,
//            same pattern as bgemm's Wt[col][k]). 4 MFMAs.
//   softmax: online, on C-layout (row=4g+r, col=key); row stats via 16-lane
//            __shfl_xor reduce. Mask: cq=-2 if smq else sid ; ck=-1 if smk
//            else sid ; masked <=> cq != ck  (reproduces finfo.min semantics;
//            fully-masked rows degrade to uniform attention like the ref).
//   P->PV  : per-wave LDS round-trip, XOR-swizzled (byte ^= (row&7)<<4 on
//            both write and read — same involution, G4).
//   PV     : A-frag = P, B-frag = Vt (V transposed into LDS [32][72]).
// ---------------------------------------------------------------------------
__global__ __launch_bounds__(256) void attn_mfma_k(
    const unsigned short* __restrict__ qkv, const int* __restrict__ sids,
    const int* __restrict__ smask, unsigned short* __restrict__ out)
{
    __shared__ unsigned short Vt[32][72];     // [d][key], pad 64->72 (rows 144B, 16B-aligned)
    __shared__ int ck[64];
    __shared__ unsigned short P[4][16][64];   // per-wave P tile (XOR-swizzled cols)

    const int tid  = threadIdx.x;
    const int lane = tid & 63;
    const int wave = tid >> 6;
    const int g = lane >> 4;                  // 0..3
    const int c = lane & 15;

    const int bh = blockIdx.x >> 4;           // 16 q-tiles per (b,h)
    const int qt = blockIdx.x & 15;
    const int b = bh / HH, h = bh % HH;
    const int q0w = qt * 64 + wave * 16;
    const size_t qrow = 3 * DD;               // 1152

    // Q A-frag: row = c (q in tile), k-elems = d = g*8..g*8+7 (16B contiguous)
    const short8 qf = *(const short8*)&qkv[(size_t)(b * NN + q0w + c) * qrow + h * HDD + g * 8];

    // combined query ids for this lane's 4 output rows (q = q0w + 4g + r)
    int cq[4];
    #pragma unroll
    for (int r = 0; r < 4; ++r) {
        int qq = b * NN + q0w + 4 * g + r;
        cq[r] = smask[qq] ? -2 : sids[qq];
    }

    float m[4] = {-INFINITY, -INFINITY, -INFINITY, -INFINITY};
    float l[4] = {};
    f32x4 o[2] = {};                          // O[dc]: elem r -> row 4g+r, col dc*16+c
    const f32x4 zero = {};
    const float scale = 0.17677669529663687f; // HD^-0.5
    const float FMIN = -3.402823466e38f;

    for (int kt = 0; kt < NN / 64; ++kt) {
        const int kb = kt * 64;
        // ---- stage V transposed + combined key ids
        {
            int key = tid & 63;
            int d8  = (tid >> 6) * 8;
            short8 v = *(const short8*)&qkv[(size_t)(b * NN + kb + key) * qrow + 2 * DD + h * HDD + d8];
            #pragma unroll
            for (int e = 0; e < 8; ++e)
                Vt[d8 + e][key] = (unsigned short)v[e];
            if (tid < 64) {
                int kk = b * NN + kb + tid;
                ck[tid] = smask[kk] ? -1 : sids[kk];
            }
        }
        __syncthreads();

        // ---- S = Q K^T : 4 MFMAs over 16-key subtiles
        f32x4 s4[4];
        #pragma unroll
        for (int j = 0; j < 4; ++j) {
            short8 kf = *(const short8*)&qkv[(size_t)(b * NN + kb + 16 * j + c) * qrow + DD + h * HDD + g * 8];
            s4[j] = __builtin_amdgcn_mfma_f32_16x16x32_bf16(qf, kf, zero, 0, 0, 0);
        }

        // ---- mask + scale + per-row tile max
        float pm[4] = {FMIN, FMIN, FMIN, FMIN};
        #pragma unroll
        for (int j = 0; j < 4; ++j) {
            const int ckj = ck[16 * j + c];
            #pragma unroll
            for (int r = 0; r < 4; ++r) {
                float sv = (cq[r] != ckj) ? FMIN : s4[j][r] * scale;
                s4[j][r] = sv;
                pm[r] = fmaxf(pm[r], sv);
            }
        }
        #pragma unroll
        for (int off = 1; off < 16; off <<= 1)
            #pragma unroll
            for (int r = 0; r < 4; ++r)
                pm[r] = fmaxf(pm[r], __shfl_xor(pm[r], off));

        // ---- online update
        float fac[4], psum[4];
        #pragma unroll
        for (int r = 0; r < 4; ++r) {
            float mn = fmaxf(m[r], pm[r]);
            fac[r] = __expf(m[r] - mn);       // -inf - finite -> 0 (first tile)
            m[r] = mn;
            psum[r] = 0.f;
        }
        #pragma unroll
        for (int j = 0; j < 4; ++j) {
            #pragma unroll
            for (int r = 0; r < 4; ++r) {
                float p = __expf(s4[j][r] - m[r]);
                psum[r] += p;
                int row  = 4 * g + r;
                int colb = (2 * (16 * j + c)) ^ ((row & 7) << 4);
                *(unsigned short*)((char*)&P[wave][row][0] + colb) = f2b(p);
            }
        }
        #pragma unroll
        for (int off = 1; off < 16; off <<= 1)
            #pragma unroll
            for (int r = 0; r < 4; ++r)
                psum[r] += __shfl_xor(psum[r], off);
        #pragma unroll
        for (int r = 0; r < 4; ++r) l[r] = l[r] * fac[r] + psum[r];

        #pragma unroll
        for (int dc = 0; dc < 2; ++dc)
            #pragma unroll
            for (int r = 0; r < 4; ++r)
                o[dc][r] *= fac[r];

        // ---- PV: A-frag = P (row=c, k-elems = 8 keys), B-frag = Vt
        #pragma unroll
        for (int kc = 0; kc < 2; ++kc) {
            int colb = (2 * (kc * 32 + g * 8)) ^ ((c & 7) << 4);
            short8 pf = *(const short8*)((char*)&P[wave][c][0] + colb);
            #pragma unroll
            for (int dc = 0; dc < 2; ++dc) {
                short8 vf = *(const short8*)&Vt[dc * 16 + c][kc * 32 + g * 8];
                o[dc] = __builtin_amdgcn_mfma_f32_16x16x32_bf16(pf, vf, o[dc], 0, 0, 0);
            }
        }
        __syncthreads();
    }

    // ---- normalize + write out (bf16 [M][D], heads concatenated)
    #pragma unroll
    for (int r = 0; r < 4; ++r) {
        const float inv = 1.0f / l[r];
        unsigned short* op = &out[(size_t)(b * NN + q0w + 4 * g + r) * DD + h * HDD];
        #pragma unroll
        for (int dc = 0; dc < 2; ++dc)
            op[dc * 16 + c] = f2b(o[dc][r] * inv);
    }
}

// ---------------------------------------------------------------------------
extern "C" void kernel_launch(void* const* d_in, const int* in_sizes, int n_in,
                              void* d_out, int out_size, void* d_ws, size_t ws_size,
                              hipStream_t stream)
{
    const float* x        = (const float*)d_in[0];
    const int*   hids     = (const int*)d_in[1];
    const int*   wids     = (const int*)d_in[2];
    const void*  tmask_rw = d_in[3];
    const int*   sids     = (const int*)d_in[4];
    const void*  smask_rw = d_in[5];
    const float* embed_w  = (const float*)d_in[7];
    const float* embed_b  = (const float*)d_in[8];
    const float* h_embed  = (const float*)d_in[9];
    const float* w_embed  = (const float*)d_in[10];
    const float* mtok     = (const float*)d_in[11];
    const float* norm1_w  = (const float*)d_in[12];
    const float* norm1_b  = (const float*)d_in[13];
    const float* ls1      = (const float*)d_in[14];
    const float* qkv_w    = (const float*)d_in[15];
    const float* qkv_b    = (const float*)d_in[16];
    const float* proj_w   = (const float*)d_in[17];
    const float* proj_b   = (const float*)d_in[18];
    const float* norm2_w  = (const float*)d_in[19];
    const float* norm2_b  = (const float*)d_in[20];
    const float* fc1_w    = (const float*)d_in[21];
    const float* fc1_b    = (const float*)d_in[22];
    const float* fc2_w    = (const float*)d_in[23];
    const float* fc2_b    = (const float*)d_in[24];
    const float* ls2      = (const float*)d_in[25];
    const float* pnorm_w  = (const float*)d_in[26];
    const float* pnorm_b  = (const float*)d_in[27];
    const float* pproj_w  = (const float*)d_in[28];
    const float* pproj_b  = (const float*)d_in[29];

    const size_t MD = (size_t)MM * DD;
    float*          h    = (float*)d_ws;
    unsigned short* zb   = (unsigned short*)(h + MD);
    unsigned short* hid  = zb + MD;                 // 4*MD ushorts
    unsigned short* qkvb = hid;                     // alias (disjoint liveness)
    float*          zf   = (float*)hid;             // alias: pnorm out
    unsigned short* wT   = hid + 4 * MD;
    const size_t qkvTsz  = (size_t)LL * 3 * DD * DD;
    const size_t projTsz = (size_t)LL * DD * DD;
    const size_t fc1Tsz  = (size_t)LL * DD * 4 * DD;
    unsigned short* qkvT = wT;
    unsigned short* projT = qkvT + qkvTsz;
    unsigned short* fc1T  = projT + projTsz;
    unsigned short* fc2T  = fc1T + fc1Tsz;
    int* tm32 = (int*)(fc2T + fc1Tsz);
    int* sm32 = tm32 + MM;

    cvt_mask_k<<<1, 1024, 0, stream>>>(tmask_rw, MM, tm32);
    cvt_mask_k<<<1, 1024, 0, stream>>>(smask_rw, MM, sm32);

    dim3 t256(256);
    tcast_k<<<dim3(DD/32, 3*DD/32, LL), t256, 0, stream>>>(qkv_w, qkvT, DD, 3*DD);
    tcast_k<<<dim3(DD/32, DD/32,   LL), t256, 0, stream>>>(proj_w, projT, DD, DD);
    tcast_k<<<dim3(DD/32, 4*DD/32, LL), t256, 0, stream>>>(fc1_w, fc1T, DD, 4*DD);
    tcast_k<<<dim3(4*DD/32, DD/32, LL), t256, 0, stream>>>(fc2_w, fc2T, 4*DD, DD);

    gemm_k<1><<<dim3(MM/128, DD/64), t256, 0, stream>>>(
        x, embed_w, embed_b, h, DIN, DD, tm32, hids, wids, mtok, h_embed, w_embed);

    for (int i = 0; i < LL; ++i) {
        ln_k<1><<<MM/4, t256, 0, stream>>>(h, norm1_w + i*DD, norm1_b + i*DD, zb);
        bgemm_k<0><<<dim3(MM/128, 3*DD/128), t256, 0, stream>>>(
            zb, qkvT + (size_t)i*3*DD*DD, qkv_b + i*3*DD, qkvb, DD, 3*DD, nullptr);
        attn_mfma_k<<<dim3(BB*HH*(NN/64)), t256, 0, stream>>>(qkvb, sids, sm32, zb);
        bgemm_k<2><<<dim3(MM/128, DD/128), t256, 0, stream>>>(
            zb, projT + (size_t)i*DD*DD, proj_b + i*DD, h, DD, DD, ls1 + i*DD);
        ln_k<1><<<MM/4, t256, 0, stream>>>(h, norm2_w + i*DD, norm2_b + i*DD, zb);
        bgemm_k<3><<<dim3(MM/128, 4*DD/128), t256, 0, stream>>>(
            zb, fc1T + (size_t)i*DD*4*DD, fc1_b + i*4*DD, hid, DD, 4*DD, nullptr);
        bgemm_k<2><<<dim3(MM/128, DD/128), t256, 0, stream>>>(
            hid, fc2T + (size_t)i*4*DD*DD, fc2_b + i*DD, h, 4*DD, DD, ls2 + i*DD);
    }

    ln_k<0><<<MM/4, t256, 0, stream>>>(h, pnorm_w, pnorm_b, zf);
    gemm_k<0><<<dim3(MM/128, DIN/64), t256, 0, stream>>>(
        zf, pproj_w, pproj_b, (float*)d_out, DD, DIN,
        nullptr, nullptr, nullptr, nullptr, nullptr, nullptr);
}

// Round 8
// 1352.423 us; speedup vs baseline: 3.8704x; 1.2317x over previous
//
#include <hip/hip_runtime.h>
#include <math.h>

// Problem constants
#define BB   8
#define NN   1024
#define DIN  768
#define DD   384
#define LL   6
#define HH   12
#define HDD  32
#define MM   (BB*NN)        // 8192 rows
#define EPSF 1e-5f

typedef __attribute__((ext_vector_type(8))) short short8;   // 8 bf16 (4 VGPRs)
typedef __attribute__((ext_vector_type(4))) float f32x4;    // MFMA acc

__device__ __forceinline__ unsigned short f2b(float f) {    // RNE fp32->bf16
    unsigned int u = __builtin_bit_cast(unsigned int, f);
    u = (u + 0x7fffu + ((u >> 16) & 1u)) >> 16;
    return (unsigned short)u;
}
__device__ __forceinline__ float b2f(unsigned short h) {
    return __builtin_bit_cast(float, ((unsigned int)h) << 16);
}

// ---------------------------------------------------------------------------
// Bool-mask normalization (layout auto-detected; see round-2 note).
// ---------------------------------------------------------------------------
__global__ __launch_bounds__(1024) void cvt_mask_k(const void* __restrict__ src,
                                                   int n, int* __restrict__ dst)
{
    __shared__ int flag;
    if (threadIdx.x == 0) flag = 0;
    __syncthreads();
    const int* si = (const int*)src;
    int nq = n >> 2;
    int any = 0;
    for (int i = threadIdx.x; i < nq; i += blockDim.x) any |= si[i] & ~1;
    if (any) atomicOr(&flag, 1);
    __syncthreads();
    if (flag) {
        const unsigned char* sb = (const unsigned char*)src;
        for (int i = threadIdx.x; i < n; i += blockDim.x) dst[i] = sb[i];
    } else {
        for (int i = threadIdx.x; i < n; i += blockDim.x) dst[i] = si[i];
    }
}

// ---------------------------------------------------------------------------
// Per-(b, key-tile-of-64) min/max of unmasked sequence ids (for tile skipping)
// ---------------------------------------------------------------------------
__global__ __launch_bounds__(64) void kminmax_k(const int* __restrict__ sids,
                                                const int* __restrict__ smask,
                                                int2* __restrict__ kmm)
{
    int e = blockIdx.x;            // 0..127 : b*16 + kt
    int b = e >> 4, kt = e & 15;
    int lane = threadIdx.x;
    int kk = b * NN + kt * 64 + lane;
    int s = sids[kk];
    int msk = smask[kk];
    int mn = msk ? 0x7fffffff : s;
    int mx = msk ? (int)0x80000000 : s;
    #pragma unroll
    for (int off = 32; off; off >>= 1) {
        mn = min(mn, __shfl_xor(mn, off));
        mx = max(mx, __shfl_xor(mx, off));
    }
    if (lane == 0) kmm[e] = make_int2(mn, mx);
}

// ---------------------------------------------------------------------------
// Per-(b,h) mean of V over all N keys (uniform-attention output for globally
// masked query rows — reference semantics of softmax over an all-min row).
// ---------------------------------------------------------------------------
__global__ __launch_bounds__(256) void vmean_k(const unsigned short* __restrict__ qkv,
                                               unsigned short* __restrict__ vmean)
{
    __shared__ float part[8][32];
    int bh = blockIdx.x;            // 0..95
    int b = bh / HH, h = bh % HH;
    int d = threadIdx.x & 31, grp = threadIdx.x >> 5;
    const unsigned short* vp = qkv + (size_t)(b * NN + grp * 128) * (3 * DD)
                                   + 2 * DD + h * HDD + d;
    float s = 0.f;
    for (int n = 0; n < 128; ++n)
        s += b2f(vp[(size_t)n * 3 * DD]);
    part[grp][d] = s;
    __syncthreads();
    if (grp == 0) {
        float t = 0.f;
        #pragma unroll
        for (int g2 = 0; g2 < 8; ++g2) t += part[g2][d];
        vmean[bh * HDD + d] = f2b(t * (1.0f / NN));
    }
}

// ---------------------------------------------------------------------------
// Weight transpose+cast: W fp32 [K][N] -> Wt bf16 [N][K]; one layer per blockIdx.z
// ---------------------------------------------------------------------------
__global__ __launch_bounds__(256) void tcast_k(const float* __restrict__ W,
                                               unsigned short* __restrict__ Wt,
                                               int K, int N)
{
    __shared__ float tile[32][33];
    const size_t lstr = (size_t)K * N;
    const float* Wl = W + blockIdx.z * lstr;
    unsigned short* Wtl = Wt + blockIdx.z * lstr;
    int k0 = blockIdx.x * 32, n0 = blockIdx.y * 32;
    int tx = threadIdx.x & 31, ty = threadIdx.x >> 5;      // ty 0..7
    #pragma unroll
    for (int r = 0; r < 32; r += 8)
        tile[ty + r][tx] = Wl[(size_t)(k0 + ty + r) * N + n0 + tx];
    __syncthreads();
    #pragma unroll
    for (int r = 0; r < 32; r += 8)
        Wtl[(size_t)(n0 + ty + r) * K + k0 + tx] = f2b(tile[tx][ty + r]);
}

// ---------------------------------------------------------------------------
// bf16 MFMA GEMM: C[M x NO] = A[M x K] @ W[K x NO]
//   A  : bf16 [M][K] row-major ; Wt : bf16 [NO][K] (pre-transposed weights)
// Tile 128x128, BK=32, 4 waves (2x2), 64x64/wave = 4x4 frags of 16x16x32.
// EPI: 0 = bias -> bf16 out ; 2 = h += ls*(acc+bias) (fp32) ; 3 = gelu -> bf16
// ---------------------------------------------------------------------------
template <int EPI>
__global__ __launch_bounds__(256) void bgemm_k(
    const unsigned short* __restrict__ A, const unsigned short* __restrict__ Wt,
    const float* __restrict__ bias, void* __restrict__ out,
    int K, int NO, const float* __restrict__ ls)
{
    __shared__ unsigned short As[128][40];
    __shared__ unsigned short Bs[128][40];

    const int tid  = threadIdx.x;
    const int lane = tid & 63;
    const int wave = tid >> 6;
    const int wr = wave >> 1, wc = wave & 1;
    const int rowBase = blockIdx.x * 128;
    const int colBase = blockIdx.y * 128;
    const int rr = lane & 15;
    const int kr = (lane >> 4) * 8;

    f32x4 acc[4][4] = {};

    for (int k0 = 0; k0 < K; k0 += 32) {
        #pragma unroll
        for (int i = 0; i < 2; ++i) {
            int s   = tid + i * 256;       // 0..511
            int row = s >> 2;              // 0..127
            int seg = (s & 3) * 8;         // bf16 offset 0,8,16,24
            *(short8*)&As[row][seg] =
                *(const short8*)&A[(size_t)(rowBase + row) * K + k0 + seg];
            *(short8*)&Bs[row][seg] =
                *(const short8*)&Wt[(size_t)(colBase + row) * K + k0 + seg];
        }
        __syncthreads();

        short8 af[4], bfr[4];
        #pragma unroll
        for (int i = 0; i < 4; ++i)
            af[i] = *(const short8*)&As[wr * 64 + i * 16 + rr][kr];
        #pragma unroll
        for (int j = 0; j < 4; ++j)
            bfr[j] = *(const short8*)&Bs[wc * 64 + j * 16 + rr][kr];
        #pragma unroll
        for (int i = 0; i < 4; ++i)
            #pragma unroll
            for (int j = 0; j < 4; ++j)
                acc[i][j] = __builtin_amdgcn_mfma_f32_16x16x32_bf16(
                    af[i], bfr[j], acc[i][j], 0, 0, 0);
        __syncthreads();
    }

    // epilogue: D element (row=(lane>>4)*4+r, col=lane&15) per 16x16 frag [m89]
    const int colq = colBase + wc * 64 + rr;
    const int rq0  = rowBase + wr * 64 + (lane >> 4) * 4;
    #pragma unroll
    for (int j = 0; j < 4; ++j) {
        const int col = colq + j * 16;
        const float bi = bias[col];
        float lsv = 0.f;
        if constexpr (EPI == 2) lsv = ls[col];
        #pragma unroll
        for (int i = 0; i < 4; ++i) {
            #pragma unroll
            for (int r = 0; r < 4; ++r) {
                const int row = rq0 + i * 16 + r;
                float v = acc[i][j][r] + bi;
                if constexpr (EPI == 0) {
                    ((unsigned short*)out)[(size_t)row * NO + col] = f2b(v);
                } else if constexpr (EPI == 2) {
                    float* hp = (float*)out + (size_t)row * NO + col;
                    *hp += lsv * v;
                } else {  // gelu (exact) -> bf16
                    float g = 0.5f * v * (1.0f + erff(v * 0.70710678118654752f));
                    ((unsigned short*)out)[(size_t)row * NO + col] = f2b(g);
                }
            }
        }
    }
}

// ---------------------------------------------------------------------------
// fp32 GEMM (embed + pproj only — full-scale precision paths stay fp32)
// EPI: 0=bias  1=embed(bias,mask_token,pos-embeds)
// ---------------------------------------------------------------------------
template <int EPI>
__global__ __launch_bounds__(256) void gemm_k(
    const float* __restrict__ A, const float* __restrict__ Wt,
    const float* __restrict__ bias, float* __restrict__ C,
    int K, int NO,
    const int* __restrict__ tmask, const int* __restrict__ hids,
    const int* __restrict__ wids, const float* __restrict__ mtok,
    const float* __restrict__ hemb, const float* __restrict__ wemb)
{
    __shared__ float As[16][132];
    __shared__ float Bs[16][64];

    const int tid = threadIdx.x;
    const int tx = tid & 15;
    const int ty = tid >> 4;
    const int rowBase = blockIdx.x * 128;
    const int colBase = blockIdx.y * 64;

    float acc[8][4] = {};

    for (int k0 = 0; k0 < K; k0 += 16) {
        #pragma unroll
        for (int i = 0; i < 2; ++i) {
            int s   = tid + i * 256;
            int row = s >> 2;
            int kq  = (s & 3) * 4;
            float4 av = *(const float4*)(&A[(size_t)(rowBase + row) * K + k0 + kq]);
            As[kq + 0][row] = av.x;
            As[kq + 1][row] = av.y;
            As[kq + 2][row] = av.z;
            As[kq + 3][row] = av.w;
        }
        {
            int r = tid >> 4;
            int c = (tid & 15) * 4;
            *(float4*)(&Bs[r][c]) =
                *(const float4*)(&Wt[(size_t)(k0 + r) * NO + colBase + c]);
        }
        __syncthreads();

        #pragma unroll
        for (int k = 0; k < 16; ++k) {
            float4 b4 = *(const float4*)(&Bs[k][tx * 4]);
            float4 a0 = *(const float4*)(&As[k][ty * 8]);
            float4 a1 = *(const float4*)(&As[k][ty * 8 + 4]);
            float a[8] = {a0.x, a0.y, a0.z, a0.w, a1.x, a1.y, a1.z, a1.w};
            float b[4] = {b4.x, b4.y, b4.z, b4.w};
            #pragma unroll
            for (int i = 0; i < 8; ++i)
                #pragma unroll
                for (int j = 0; j < 4; ++j)
                    acc[i][j] = fmaf(a[i], b[j], acc[i][j]);
        }
        __syncthreads();
    }

    const int cb = colBase + tx * 4;
    float4 bi = *(const float4*)(&bias[cb]);
    #pragma unroll
    for (int i = 0; i < 8; ++i) {
        int r = rowBase + ty * 8 + i;
        float v[4];
        #pragma unroll
        for (int j = 0; j < 4; ++j) v[j] = acc[i][j] + ((const float*)&bi)[j];

        float* cp = &C[(size_t)r * NO + cb];
        if constexpr (EPI == 1) {
            int tm = tmask[r];
            const float* he = &hemb[(size_t)hids[r] * DD + cb];
            const float* we = &wemb[(size_t)wids[r] * DD + cb];
            float4 o;
            #pragma unroll
            for (int j = 0; j < 4; ++j) {
                float x = tm ? mtok[cb + j] : v[j];
                ((float*)&o)[j] = x + he[j] + we[j];
            }
            *(float4*)cp = o;
        } else {
            float4 o = {v[0], v[1], v[2], v[3]};
            *(float4*)cp = o;
        }
    }
}

// ---------------------------------------------------------------------------
// LayerNorm: one wave per row. OUT: 0 = fp32, 1 = bf16
// ---------------------------------------------------------------------------
template <int OUT>
__global__ __launch_bounds__(256) void ln_k(
    const float* __restrict__ X, const float* __restrict__ w,
    const float* __restrict__ b, void* __restrict__ Y)
{
    int row  = blockIdx.x * 4 + (threadIdx.x >> 6);
    int lane = threadIdx.x & 63;
    const float* xr = X + (size_t)row * DD;

    float x[6];
    #pragma unroll
    for (int j = 0; j < 6; ++j) x[j] = xr[lane + 64 * j];

    float s = 0.f;
    #pragma unroll
    for (int j = 0; j < 6; ++j) s += x[j];
    #pragma unroll
    for (int off = 32; off > 0; off >>= 1) s += __shfl_xor(s, off);
    float mu = s * (1.0f / 384.0f);

    float v = 0.f;
    #pragma unroll
    for (int j = 0; j < 6; ++j) { float d = x[j] - mu; v += d * d; }
    #pragma unroll
    for (int off = 32; off > 0; off >>= 1) v += __shfl_xor(v, off);
    float rstd = rsqrtf(v * (1.0f / 384.0f) + EPSF);

    #pragma unroll
    for (int j = 0; j < 6; ++j) {
        int c = lane + 64 * j;
        float y = (x[j] - mu) * rstd * w[c] + b[c];
        if constexpr (OUT == 0) ((float*)Y)[(size_t)row * DD + c] = y;
        else ((unsigned short*)Y)[(size_t)row * DD + c] = f2b(y);
    }
}

// ---------------------------------------------------------------------------
// MFMA flash attention with block-diagonal tile skipping.
// Block = 4 waves; wave owns 16 queries; block = 64 queries of (b,h).
// Sequences are sorted -> a block's queries span a small sid range; key tiles
// whose unmasked-sid range doesn't intersect are skipped (block-uniform).
// Globally-masked query rows (cq==-2) never match -> epilogue writes Vmean
// (reference semantics: softmax over all-finfo.min row = uniform over all keys).
// Correctness of skipping for normal rows: own key tile always overlaps (own
// sid in both ranges) so m >= own-score (finite); masked keys in processed
// tiles give exp(FMIN-m)=0 exactly as in the full loop.
// ---------------------------------------------------------------------------
__global__ __launch_bounds__(256) void attn_mfma_k(
    const unsigned short* __restrict__ qkv, const int* __restrict__ sids,
    const int* __restrict__ smask, const int2* __restrict__ kmm,
    const unsigned short* __restrict__ vmean, unsigned short* __restrict__ out)
{
    __shared__ unsigned short Vt[32][72];     // [d][key], pad 64->72
    __shared__ int ck[64];
    __shared__ unsigned short P[4][16][64];   // per-wave P tile (XOR-swizzled cols)
    __shared__ int qmn[4], qmx[4];

    const int tid  = threadIdx.x;
    const int lane = tid & 63;
    const int wave = tid >> 6;
    const int g = lane >> 4;                  // 0..3
    const int c = lane & 15;

    const int bh = blockIdx.x >> 4;           // 16 q-tiles per (b,h)
    const int qt = blockIdx.x & 15;
    const int b = bh / HH, h = bh % HH;
    const int q0w = qt * 64 + wave * 16;
    const size_t qrow = 3 * DD;               // 1152

    // Q A-frag: row = c (q in tile), k-elems = d = g*8..g*8+7
    const short8 qf = *(const short8*)&qkv[(size_t)(b * NN + q0w + c) * qrow + h * HDD + g * 8];

    // combined query ids for this lane's 4 output rows (q = q0w + 4g + r)
    int cq[4];
    #pragma unroll
    for (int r = 0; r < 4; ++r) {
        int qq = b * NN + q0w + 4 * g + r;
        cq[r] = smask[qq] ? -2 : sids[qq];
    }

    // block-wide query sid range (over non-masked rows)
    {
        int lmin = 0x7fffffff, lmax = (int)0x80000000;
        #pragma unroll
        for (int r = 0; r < 4; ++r) {
            if (cq[r] != -2) { lmin = min(lmin, cq[r]); lmax = max(lmax, cq[r]); }
        }
        #pragma unroll
        for (int off = 32; off; off >>= 1) {
            lmin = min(lmin, __shfl_xor(lmin, off));
            lmax = max(lmax, __shfl_xor(lmax, off));
        }
        if (lane == 0) { qmn[wave] = lmin; qmx[wave] = lmax; }
    }
    __syncthreads();
    int qminb = min(min(qmn[0], qmn[1]), min(qmn[2], qmn[3]));
    int qmaxb = max(max(qmx[0], qmx[1]), max(qmx[2], qmx[3]));

    float m[4] = {-INFINITY, -INFINITY, -INFINITY, -INFINITY};
    float l[4] = {};
    f32x4 o[2] = {};                          // O[dc]: elem r -> row 4g+r, col dc*16+c
    const f32x4 zero = {};
    const float scale = 0.17677669529663687f; // HD^-0.5
    const float FMIN = -3.402823466e38f;

    for (int kt = 0; kt < NN / 64; ++kt) {
        const int2 kr = kmm[(b << 4) + kt];
        if (kr.x > qmaxb || kr.y < qminb) continue;   // block-uniform skip

        const int kb = kt * 64;
        // ---- stage V transposed + combined key ids
        {
            int key = tid & 63;
            int d8  = (tid >> 6) * 8;
            short8 v = *(const short8*)&qkv[(size_t)(b * NN + kb + key) * qrow + 2 * DD + h * HDD + d8];
            #pragma unroll
            for (int e = 0; e < 8; ++e)
                Vt[d8 + e][key] = (unsigned short)v[e];
            if (tid < 64) {
                int kk = b * NN + kb + tid;
                ck[tid] = smask[kk] ? -1 : sids[kk];
            }
        }
        __syncthreads();

        // ---- S = Q K^T : 4 MFMAs over 16-key subtiles
        f32x4 s4[4];
        #pragma unroll
        for (int j = 0; j < 4; ++j) {
            short8 kf = *(const short8*)&qkv[(size_t)(b * NN + kb + 16 * j + c) * qrow + DD + h * HDD + g * 8];
            s4[j] = __builtin_amdgcn_mfma_f32_16x16x32_bf16(qf, kf, zero, 0, 0, 0);
        }

        // ---- mask + scale + per-row tile max
        float pm[4] = {FMIN, FMIN, FMIN, FMIN};
        #pragma unroll
        for (int j = 0; j < 4; ++j) {
            const int ckj = ck[16 * j + c];
            #pragma unroll
            for (int r = 0; r < 4; ++r) {
                float sv = (cq[r] != ckj) ? FMIN : s4[j][r] * scale;
                s4[j][r] = sv;
                pm[r] = fmaxf(pm[r], sv);
            }
        }
        #pragma unroll
        for (int off = 1; off < 16; off <<= 1)
            #pragma unroll
            for (int r = 0; r < 4; ++r)
                pm[r] = fmaxf(pm[r], __shfl_xor(pm[r], off));

        // ---- online update
        float fac[4], psum[4];
        #pragma unroll
        for (int r = 0; r < 4; ++r) {
            float mn = fmaxf(m[r], pm[r]);
            fac[r] = __expf(m[r] - mn);       // -inf - finite -> 0 (first tile)
            m[r] = mn;
            psum[r] = 0.f;
        }
        #pragma unroll
        for (int j = 0; j < 4; ++j) {
            #pragma unroll
            for (int r = 0; r < 4; ++r) {
                float p = __expf(s4[j][r] - m[r]);
                psum[r] += p;
                int row  = 4 * g + r;
                int colb = (2 * (16 * j + c)) ^ ((row & 7) << 4);
                *(unsigned short*)((char*)&P[wave][row][0] + colb) = f2b(p);
            }
        }
        #pragma unroll
        for (int off = 1; off < 16; off <<= 1)
            #pragma unroll
            for (int r = 0; r < 4; ++r)
                psum[r] += __shfl_xor(psum[r], off);
        #pragma unroll
        for (int r = 0; r < 4; ++r) l[r] = l[r] * fac[r] + psum[r];

        #pragma unroll
        for (int dc = 0; dc < 2; ++dc)
            #pragma unroll
            for (int r = 0; r < 4; ++r)
                o[dc][r] *= fac[r];

        // ---- PV: A-frag = P (row=c, k-elems = 8 keys), B-frag = Vt
        #pragma unroll
        for (int kc = 0; kc < 2; ++kc) {
            int colb = (2 * (kc * 32 + g * 8)) ^ ((c & 7) << 4);
            short8 pf = *(const short8*)((char*)&P[wave][c][0] + colb);
            #pragma unroll
            for (int dc = 0; dc < 2; ++dc) {
                short8 vf = *(const short8*)&Vt[dc * 16 + c][kc * 32 + g * 8];
                o[dc] = __builtin_amdgcn_mfma_f32_16x16x32_bf16(pf, vf, o[dc], 0, 0, 0);
            }
        }
        __syncthreads();
    }

    // ---- normalize + write out (bf16 [M][D], heads concatenated)
    #pragma unroll
    for (int r = 0; r < 4; ++r) {
        unsigned short* op = &out[(size_t)(b * NN + q0w + 4 * g + r) * DD + h * HDD];
        if (cq[r] == -2) {                    // fully-masked row: uniform attn
            #pragma unroll
            for (int dc = 0; dc < 2; ++dc)
                op[dc * 16 + c] = vmean[bh * HDD + dc * 16 + c];
        } else {
            const float inv = 1.0f / l[r];
            #pragma unroll
            for (int dc = 0; dc < 2; ++dc)
                op[dc * 16 + c] = f2b(o[dc][r] * inv);
        }
    }
}

// ---------------------------------------------------------------------------
extern "C" void kernel_launch(void* const* d_in, const int* in_sizes, int n_in,
                              void* d_out, int out_size, void* d_ws, size_t ws_size,
                              hipStream_t stream)
{
    const float* x        = (const float*)d_in[0];
    const int*   hids     = (const int*)d_in[1];
    const int*   wids     = (const int*)d_in[2];
    const void*  tmask_rw = d_in[3];
    const int*   sids     = (const int*)d_in[4];
    const void*  smask_rw = d_in[5];
    const float* embed_w  = (const float*)d_in[7];
    const float* embed_b  = (const float*)d_in[8];
    const float* h_embed  = (const float*)d_in[9];
    const float* w_embed  = (const float*)d_in[10];
    const float* mtok     = (const float*)d_in[11];
    const float* norm1_w  = (const float*)d_in[12];
    const float* norm1_b  = (const float*)d_in[13];
    const float* ls1      = (const float*)d_in[14];
    const float* qkv_w    = (const float*)d_in[15];
    const float* qkv_b    = (const float*)d_in[16];
    const float* proj_w   = (const float*)d_in[17];
    const float* proj_b   = (const float*)d_in[18];
    const float* norm2_w  = (const float*)d_in[19];
    const float* norm2_b  = (const float*)d_in[20];
    const float* fc1_w    = (const float*)d_in[21];
    const float* fc1_b    = (const float*)d_in[22];
    const float* fc2_w    = (const float*)d_in[23];
    const float* fc2_b    = (const float*)d_in[24];
    const float* ls2      = (const float*)d_in[25];
    const float* pnorm_w  = (const float*)d_in[26];
    const float* pnorm_b  = (const float*)d_in[27];
    const float* pproj_w  = (const float*)d_in[28];
    const float* pproj_b  = (const float*)d_in[29];

    const size_t MD = (size_t)MM * DD;
    float*          h    = (float*)d_ws;
    unsigned short* zb   = (unsigned short*)(h + MD);
    unsigned short* hid  = zb + MD;                 // 4*MD ushorts
    unsigned short* qkvb = hid;                     // alias (disjoint liveness)
    float*          zf   = (float*)hid;             // alias: pnorm out
    unsigned short* wT   = hid + 4 * MD;
    const size_t qkvTsz  = (size_t)LL * 3 * DD * DD;
    const size_t projTsz = (size_t)LL * DD * DD;
    const size_t fc1Tsz  = (size_t)LL * DD * 4 * DD;
    unsigned short* qkvT = wT;
    unsigned short* projT = qkvT + qkvTsz;
    unsigned short* fc1T  = projT + projTsz;
    unsigned short* fc2T  = fc1T + fc1Tsz;
    int* tm32 = (int*)(fc2T + fc1Tsz);
    int* sm32 = tm32 + MM;
    unsigned short* vmean = (unsigned short*)(sm32 + MM);   // 96*32 bf16
    int2* kmm = (int2*)(vmean + BB * HH * HDD);             // 128 int2

    cvt_mask_k<<<1, 1024, 0, stream>>>(tmask_rw, MM, tm32);
    cvt_mask_k<<<1, 1024, 0, stream>>>(smask_rw, MM, sm32);
    kminmax_k<<<BB * 16, 64, 0, stream>>>(sids, sm32, kmm);

    dim3 t256(256);
    tcast_k<<<dim3(DD/32, 3*DD/32, LL), t256, 0, stream>>>(qkv_w, qkvT, DD, 3*DD);
    tcast_k<<<dim3(DD/32, DD/32,   LL), t256, 0, stream>>>(proj_w, projT, DD, DD);
    tcast_k<<<dim3(DD/32, 4*DD/32, LL), t256, 0, stream>>>(fc1_w, fc1T, DD, 4*DD);
    tcast_k<<<dim3(4*DD/32, DD/32, LL), t256, 0, stream>>>(fc2_w, fc2T, 4*DD, DD);

    gemm_k<1><<<dim3(MM/128, DD/64), t256, 0, stream>>>(
        x, embed_w, embed_b, h, DIN, DD, tm32, hids, wids, mtok, h_embed, w_embed);

    for (int i = 0; i < LL; ++i) {
        ln_k<1><<<MM/4, t256, 0, stream>>>(h, norm1_w + i*DD, norm1_b + i*DD, zb);
        bgemm_k<0><<<dim3(MM/128, 3*DD/128), t256, 0, stream>>>(
            zb, qkvT + (size_t)i*3*DD*DD, qkv_b + i*3*DD, qkvb, DD, 3*DD, nullptr);
        vmean_k<<<BB * HH, t256, 0, stream>>>(qkvb, vmean);
        attn_mfma_k<<<dim3(BB*HH*(NN/64)), t256, 0, stream>>>(
            qkvb, sids, sm32, kmm, vmean, zb);
        bgemm_k<2><<<dim3(MM/128, DD/128), t256, 0, stream>>>(
            zb, projT + (size_t)i*DD*DD, proj_b + i*DD, h, DD, DD, ls1 + i*DD);
        ln_k<1><<<MM/4, t256, 0, stream>>>(h, norm2_w + i*DD, norm2_b + i*DD, zb);
        bgemm_k<3><<<dim3(MM/128, 4*DD/128), t256, 0, stream>>>(
            zb, fc1T + (size_t)i*DD*4*DD, fc1_b + i*4*DD, hid, DD, 4*DD, nullptr);
        bgemm_k<2><<<dim3(MM/128, DD/128), t256, 0, stream>>>(
            hid, fc2T + (size_t)i*4*DD*DD, fc2_b + i*DD, h, 4*DD, DD, ls2 + i*DD);
    }

    ln_k<0><<<MM/4, t256, 0, stream>>>(h, pnorm_w, pnorm_b, zf);
    gemm_k<0><<<dim3(MM/128, DIN/64), t256, 0, stream>>>(
        zf, pproj_w, pproj_b, (float*)d_out, DD, DIN,
        nullptr, nullptr, nullptr, nullptr, nullptr, nullptr);
}

// Round 9
// 1289.423 us; speedup vs baseline: 4.0595x; 1.0489x over previous
//
#include <hip/hip_runtime.h>
#include <math.h>

// Problem constants
#define BB   8
#define NN   1024
#define DIN  768
#define DD   384
#define LL   6
#define HH   12
#define HDD  32
#define MM   (BB*NN)        // 8192 rows
#define EPSF 1e-5f

typedef __attribute__((ext_vector_type(8))) short short8;   // 8 bf16 (4 VGPRs)
typedef __attribute__((ext_vector_type(4))) float f32x4;    // MFMA acc

__device__ __forceinline__ unsigned short f2b(float f) {    // RNE fp32->bf16
    unsigned int u = __builtin_bit_cast(unsigned int, f);
    u = (u + 0x7fffu + ((u >> 16) & 1u)) >> 16;
    return (unsigned short)u;
}
__device__ __forceinline__ float b2f(unsigned short h) {
    return __builtin_bit_cast(float, ((unsigned int)h) << 16);
}

// ---------------------------------------------------------------------------
// Bool-mask normalization (layout auto-detected; see round-2 note).
// ---------------------------------------------------------------------------
__global__ __launch_bounds__(1024) void cvt_mask_k(const void* __restrict__ src,
                                                   int n, int* __restrict__ dst)
{
    __shared__ int flag;
    if (threadIdx.x == 0) flag = 0;
    __syncthreads();
    const int* si = (const int*)src;
    int nq = n >> 2;
    int any = 0;
    for (int i = threadIdx.x; i < nq; i += blockDim.x) any |= si[i] & ~1;
    if (any) atomicOr(&flag, 1);
    __syncthreads();
    if (flag) {
        const unsigned char* sb = (const unsigned char*)src;
        for (int i = threadIdx.x; i < n; i += blockDim.x) dst[i] = sb[i];
    } else {
        for (int i = threadIdx.x; i < n; i += blockDim.x) dst[i] = si[i];
    }
}

// ---------------------------------------------------------------------------
// Per-(b, key-tile-of-64) min/max of unmasked sequence ids (for tile skipping)
// ---------------------------------------------------------------------------
__global__ __launch_bounds__(64) void kminmax_k(const int* __restrict__ sids,
                                                const int* __restrict__ smask,
                                                int2* __restrict__ kmm)
{
    int e = blockIdx.x;            // 0..127 : b*16 + kt
    int b = e >> 4, kt = e & 15;
    int lane = threadIdx.x;
    int kk = b * NN + kt * 64 + lane;
    int s = sids[kk];
    int msk = smask[kk];
    int mn = msk ? 0x7fffffff : s;
    int mx = msk ? (int)0x80000000 : s;
    #pragma unroll
    for (int off = 32; off; off >>= 1) {
        mn = min(mn, __shfl_xor(mn, off));
        mx = max(mx, __shfl_xor(mx, off));
    }
    if (lane == 0) kmm[e] = make_int2(mn, mx);
}

// ---------------------------------------------------------------------------
// Per-(b,h) mean of V over all N keys (uniform-attention output for globally
// masked query rows — reference semantics of softmax over an all-min row).
// ---------------------------------------------------------------------------
__global__ __launch_bounds__(256) void vmean_k(const unsigned short* __restrict__ qkv,
                                               unsigned short* __restrict__ vmean)
{
    __shared__ float part[8][32];
    int bh = blockIdx.x;            // 0..95
    int b = bh / HH, h = bh % HH;
    int d = threadIdx.x & 31, grp = threadIdx.x >> 5;
    const unsigned short* vp = qkv + (size_t)(b * NN + grp * 128) * (3 * DD)
                                   + 2 * DD + h * HDD + d;
    float s = 0.f;
    for (int n = 0; n < 128; ++n)
        s += b2f(vp[(size_t)n * 3 * DD]);
    part[grp][d] = s;
    __syncthreads();
    if (grp == 0) {
        float t = 0.f;
        #pragma unroll
        for (int g2 = 0; g2 < 8; ++g2) t += part[g2][d];
        vmean[bh * HDD + d] = f2b(t * (1.0f / NN));
    }
}

// ---------------------------------------------------------------------------
// Weight transpose+cast: W fp32 [K][N] -> Wt bf16 [N][K]; one layer per blockIdx.z
// ---------------------------------------------------------------------------
__global__ __launch_bounds__(256) void tcast_k(const float* __restrict__ W,
                                               unsigned short* __restrict__ Wt,
                                               int K, int N)
{
    __shared__ float tile[32][33];
    const size_t lstr = (size_t)K * N;
    const float* Wl = W + blockIdx.z * lstr;
    unsigned short* Wtl = Wt + blockIdx.z * lstr;
    int k0 = blockIdx.x * 32, n0 = blockIdx.y * 32;
    int tx = threadIdx.x & 31, ty = threadIdx.x >> 5;      // ty 0..7
    #pragma unroll
    for (int r = 0; r < 32; r += 8)
        tile[ty + r][tx] = Wl[(size_t)(k0 + ty + r) * N + n0 + tx];
    __syncthreads();
    #pragma unroll
    for (int r = 0; r < 32; r += 8)
        Wtl[(size_t)(n0 + ty + r) * K + k0 + tx] = f2b(tile[tx][ty + r]);
}

// ---------------------------------------------------------------------------
// Weight transpose + hi/lo split: W fp32 [K][N] -> WT_hi/WT_lo bf16 [N][K].
// hi = bf16(v), lo = bf16(v - hi): combined ~16-17 mantissa bits.
// ---------------------------------------------------------------------------
__global__ __launch_bounds__(256) void tcast2_k(const float* __restrict__ W,
                                                unsigned short* __restrict__ WTh,
                                                unsigned short* __restrict__ WTl,
                                                int K, int N)
{
    __shared__ float tile[32][33];
    int k0 = blockIdx.x * 32, n0 = blockIdx.y * 32;
    int tx = threadIdx.x & 31, ty = threadIdx.x >> 5;      // ty 0..7
    #pragma unroll
    for (int r = 0; r < 32; r += 8)
        tile[ty + r][tx] = W[(size_t)(k0 + ty + r) * N + n0 + tx];
    __syncthreads();
    #pragma unroll
    for (int r = 0; r < 32; r += 8) {
        float v = tile[tx][ty + r];
        unsigned short hi = f2b(v);
        unsigned short lo = f2b(v - b2f(hi));
        size_t idx = (size_t)(n0 + ty + r) * K + k0 + tx;
        WTh[idx] = hi;
        WTl[idx] = lo;
    }
}

// ---------------------------------------------------------------------------
// Split-bf16 (bf16x3) MFMA GEMM for the full-scale fp32 paths (embed, pproj):
//   C = A@W with A fp32 [M][K], W pre-split bf16 WT_hi/lo [NO][K].
//   A*W ~= Ahi*Whi + Ahi*Wlo + Alo*Whi  (drop AloWlo ~2^-16 rel).
// Tile 128x64, BK=32, 4 waves (2x2: 64 rows x 32 cols each), 4x2 frags.
// EPI: 0 = bias -> fp32 out ; 1 = embed(bias, mask_token, pos-embeds) -> fp32
// ---------------------------------------------------------------------------
template <int EPI>
__global__ __launch_bounds__(256) void sgemm_k(
    const float* __restrict__ A,
    const unsigned short* __restrict__ WTh, const unsigned short* __restrict__ WTl,
    const float* __restrict__ bias, float* __restrict__ out,
    int K, int NO,
    const int* __restrict__ tmask, const int* __restrict__ hids,
    const int* __restrict__ wids, const float* __restrict__ mtok,
    const float* __restrict__ hemb, const float* __restrict__ wemb)
{
    __shared__ unsigned short Ah[128][40];
    __shared__ unsigned short Al[128][40];
    __shared__ unsigned short Bh[64][40];
    __shared__ unsigned short Bl[64][40];

    const int tid  = threadIdx.x;
    const int lane = tid & 63;
    const int wave = tid >> 6;
    const int wr = wave >> 1, wc = wave & 1;
    const int rowBase = blockIdx.x * 128;
    const int colBase = blockIdx.y * 64;
    const int rr = lane & 15;
    const int kr = (lane >> 4) * 8;

    f32x4 acc[4][2] = {};

    for (int k0 = 0; k0 < K; k0 += 32) {
        // --- stage A (128x32 fp32 -> hi/lo), 4 float4 per thread
        #pragma unroll
        for (int i = 0; i < 4; ++i) {
            int s   = tid + i * 256;       // 0..1023
            int row = s >> 3;              // 0..127
            int q   = (s & 7) * 4;         // 0..28
            float4 av = *(const float4*)&A[(size_t)(rowBase + row) * K + k0 + q];
            ushort4 h4, l4;
            #pragma unroll
            for (int e = 0; e < 4; ++e) {
                float v = ((const float*)&av)[e];
                unsigned short hi = f2b(v);
                ((unsigned short*)&h4)[e] = hi;
                ((unsigned short*)&l4)[e] = f2b(v - b2f(hi));
            }
            *(ushort4*)&Ah[row][q] = h4;
            *(ushort4*)&Al[row][q] = l4;
        }
        // --- stage B (64x32 bf16 hi+lo), 1 short8 each per thread
        {
            int s   = tid;                 // 0..255
            int row = s >> 2;              // 0..63
            int seg = (s & 3) * 8;
            size_t gi = (size_t)(colBase + row) * K + k0 + seg;
            *(short8*)&Bh[row][seg] = *(const short8*)&WTh[gi];
            *(short8*)&Bl[row][seg] = *(const short8*)&WTl[gi];
        }
        __syncthreads();

        short8 ah[4], al[4], bh2[2], bl2[2];
        #pragma unroll
        for (int i = 0; i < 4; ++i) {
            ah[i] = *(const short8*)&Ah[wr * 64 + i * 16 + rr][kr];
            al[i] = *(const short8*)&Al[wr * 64 + i * 16 + rr][kr];
        }
        #pragma unroll
        for (int j = 0; j < 2; ++j) {
            bh2[j] = *(const short8*)&Bh[wc * 32 + j * 16 + rr][kr];
            bl2[j] = *(const short8*)&Bl[wc * 32 + j * 16 + rr][kr];
        }
        #pragma unroll
        for (int i = 0; i < 4; ++i)
            #pragma unroll
            for (int j = 0; j < 2; ++j) {
                acc[i][j] = __builtin_amdgcn_mfma_f32_16x16x32_bf16(
                    al[i], bh2[j], acc[i][j], 0, 0, 0);
                acc[i][j] = __builtin_amdgcn_mfma_f32_16x16x32_bf16(
                    ah[i], bl2[j], acc[i][j], 0, 0, 0);
                acc[i][j] = __builtin_amdgcn_mfma_f32_16x16x32_bf16(
                    ah[i], bh2[j], acc[i][j], 0, 0, 0);
            }
        __syncthreads();
    }

    // epilogue: D element (row=(lane>>4)*4+r, col=lane&15) per 16x16 frag [m89]
    const int colq = colBase + wc * 32 + rr;
    const int rq0  = rowBase + wr * 64 + (lane >> 4) * 4;
    #pragma unroll
    for (int j = 0; j < 2; ++j) {
        const int col = colq + j * 16;
        const float bi = bias[col];
        #pragma unroll
        for (int i = 0; i < 4; ++i) {
            #pragma unroll
            for (int r = 0; r < 4; ++r) {
                const int row = rq0 + i * 16 + r;
                float v = acc[i][j][r] + bi;
                if constexpr (EPI == 1) {      // embed epilogue
                    float xv = tmask[row] ? mtok[col] : v;
                    out[(size_t)row * NO + col] = xv
                        + hemb[(size_t)hids[row] * DD + col]
                        + wemb[(size_t)wids[row] * DD + col];
                } else {
                    out[(size_t)row * NO + col] = v;
                }
            }
        }
    }
}

// ---------------------------------------------------------------------------
// bf16 MFMA GEMM: C[M x NO] = A[M x K] @ W[K x NO]
//   A  : bf16 [M][K] row-major ; Wt : bf16 [NO][K] (pre-transposed weights)
// Tile 128x128, BK=32, 4 waves (2x2), 64x64/wave = 4x4 frags of 16x16x32.
// EPI: 0 = bias -> bf16 out ; 2 = h += ls*(acc+bias) (fp32) ; 3 = gelu -> bf16
// ---------------------------------------------------------------------------
template <int EPI>
__global__ __launch_bounds__(256) void bgemm_k(
    const unsigned short* __restrict__ A, const unsigned short* __restrict__ Wt,
    const float* __restrict__ bias, void* __restrict__ out,
    int K, int NO, const float* __restrict__ ls)
{
    __shared__ unsigned short As[128][40];
    __shared__ unsigned short Bs[128][40];

    const int tid  = threadIdx.x;
    const int lane = tid & 63;
    const int wave = tid >> 6;
    const int wr = wave >> 1, wc = wave & 1;
    const int rowBase = blockIdx.x * 128;
    const int colBase = blockIdx.y * 128;
    const int rr = lane & 15;
    const int kr = (lane >> 4) * 8;

    f32x4 acc[4][4] = {};

    for (int k0 = 0; k0 < K; k0 += 32) {
        #pragma unroll
        for (int i = 0; i < 2; ++i) {
            int s   = tid + i * 256;       // 0..511
            int row = s >> 2;              // 0..127
            int seg = (s & 3) * 8;         // bf16 offset 0,8,16,24
            *(short8*)&As[row][seg] =
                *(const short8*)&A[(size_t)(rowBase + row) * K + k0 + seg];
            *(short8*)&Bs[row][seg] =
                *(const short8*)&Wt[(size_t)(colBase + row) * K + k0 + seg];
        }
        __syncthreads();

        short8 af[4], bfr[4];
        #pragma unroll
        for (int i = 0; i < 4; ++i)
            af[i] = *(const short8*)&As[wr * 64 + i * 16 + rr][kr];
        #pragma unroll
        for (int j = 0; j < 4; ++j)
            bfr[j] = *(const short8*)&Bs[wc * 64 + j * 16 + rr][kr];
        #pragma unroll
        for (int i = 0; i < 4; ++i)
            #pragma unroll
            for (int j = 0; j < 4; ++j)
                acc[i][j] = __builtin_amdgcn_mfma_f32_16x16x32_bf16(
                    af[i], bfr[j], acc[i][j], 0, 0, 0);
        __syncthreads();
    }

    // epilogue: D element (row=(lane>>4)*4+r, col=lane&15) per 16x16 frag [m89]
    const int colq = colBase + wc * 64 + rr;
    const int rq0  = rowBase + wr * 64 + (lane >> 4) * 4;
    #pragma unroll
    for (int j = 0; j < 4; ++j) {
        const int col = colq + j * 16;
        const float bi = bias[col];
        float lsv = 0.f;
        if constexpr (EPI == 2) lsv = ls[col];
        #pragma unroll
        for (int i = 0; i < 4; ++i) {
            #pragma unroll
            for (int r = 0; r < 4; ++r) {
                const int row = rq0 + i * 16 + r;
                float v = acc[i][j][r] + bi;
                if constexpr (EPI == 0) {
                    ((unsigned short*)out)[(size_t)row * NO + col] = f2b(v);
                } else if constexpr (EPI == 2) {
                    float* hp = (float*)out + (size_t)row * NO + col;
                    *hp += lsv * v;
                } else {  // gelu (exact) -> bf16
                    float g = 0.5f * v * (1.0f + erff(v * 0.70710678118654752f));
                    ((unsigned short*)out)[(size_t)row * NO + col] = f2b(g);
                }
            }
        }
    }
}

// ---------------------------------------------------------------------------
// LayerNorm: one wave per row. OUT: 0 = fp32, 1 = bf16
// ---------------------------------------------------------------------------
template <int OUT>
__global__ __launch_bounds__(256) void ln_k(
    const float* __restrict__ X, const float* __restrict__ w,
    const float* __restrict__ b, void* __restrict__ Y)
{
    int row  = blockIdx.x * 4 + (threadIdx.x >> 6);
    int lane = threadIdx.x & 63;
    const float* xr = X + (size_t)row * DD;

    float x[6];
    #pragma unroll
    for (int j = 0; j < 6; ++j) x[j] = xr[lane + 64 * j];

    float s = 0.f;
    #pragma unroll
    for (int j = 0; j < 6; ++j) s += x[j];
    #pragma unroll
    for (int off = 32; off > 0; off >>= 1) s += __shfl_xor(s, off);
    float mu = s * (1.0f / 384.0f);

    float v = 0.f;
    #pragma unroll
    for (int j = 0; j < 6; ++j) { float d = x[j] - mu; v += d * d; }
    #pragma unroll
    for (int off = 32; off > 0; off >>= 1) v += __shfl_xor(v, off);
    float rstd = rsqrtf(v * (1.0f / 384.0f) + EPSF);

    #pragma unroll
    for (int j = 0; j < 6; ++j) {
        int c = lane + 64 * j;
        float y = (x[j] - mu) * rstd * w[c] + b[c];
        if constexpr (OUT == 0) ((float*)Y)[(size_t)row * DD + c] = y;
        else ((unsigned short*)Y)[(size_t)row * DD + c] = f2b(y);
    }
}

// ---------------------------------------------------------------------------
// MFMA flash attention with block-diagonal tile skipping (see round-7 notes).
// ---------------------------------------------------------------------------
__global__ __launch_bounds__(256) void attn_mfma_k(
    const unsigned short* __restrict__ qkv, const int* __restrict__ sids,
    const int* __restrict__ smask, const int2* __restrict__ kmm,
    const unsigned short* __restrict__ vmean, unsigned short* __restrict__ out)
{
    __shared__ unsigned short Vt[32][72];     // [d][key], pad 64->72
    __shared__ int ck[64];
    __shared__ unsigned short P[4][16][64];   // per-wave P tile (XOR-swizzled cols)
    __shared__ int qmn[4], qmx[4];

    const int tid  = threadIdx.x;
    const int lane = tid & 63;
    const int wave = tid >> 6;
    const int g = lane >> 4;                  // 0..3
    const int c = lane & 15;

    const int bh = blockIdx.x >> 4;           // 16 q-tiles per (b,h)
    const int qt = blockIdx.x & 15;
    const int b = bh / HH, h = bh % HH;
    const int q0w = qt * 64 + wave * 16;
    const size_t qrow = 3 * DD;               // 1152

    // Q A-frag: row = c (q in tile), k-elems = d = g*8..g*8+7
    const short8 qf = *(const short8*)&qkv[(size_t)(b * NN + q0w + c) * qrow + h * HDD + g * 8];

    // combined query ids for this lane's 4 output rows (q = q0w + 4g + r)
    int cq[4];
    #pragma unroll
    for (int r = 0; r < 4; ++r) {
        int qq = b * NN + q0w + 4 * g + r;
        cq[r] = smask[qq] ? -2 : sids[qq];
    }

    // block-wide query sid range (over non-masked rows)
    {
        int lmin = 0x7fffffff, lmax = (int)0x80000000;
        #pragma unroll
        for (int r = 0; r < 4; ++r) {
            if (cq[r] != -2) { lmin = min(lmin, cq[r]); lmax = max(lmax, cq[r]); }
        }
        #pragma unroll
        for (int off = 32; off; off >>= 1) {
            lmin = min(lmin, __shfl_xor(lmin, off));
            lmax = max(lmax, __shfl_xor(lmax, off));
        }
        if (lane == 0) { qmn[wave] = lmin; qmx[wave] = lmax; }
    }
    __syncthreads();
    int qminb = min(min(qmn[0], qmn[1]), min(qmn[2], qmn[3]));
    int qmaxb = max(max(qmx[0], qmx[1]), max(qmx[2], qmx[3]));

    float m[4] = {-INFINITY, -INFINITY, -INFINITY, -INFINITY};
    float l[4] = {};
    f32x4 o[2] = {};                          // O[dc]: elem r -> row 4g+r, col dc*16+c
    const f32x4 zero = {};
    const float scale = 0.17677669529663687f; // HD^-0.5
    const float FMIN = -3.402823466e38f;

    for (int kt = 0; kt < NN / 64; ++kt) {
        const int2 kr = kmm[(b << 4) + kt];
        if (kr.x > qmaxb || kr.y < qminb) continue;   // block-uniform skip

        const int kb = kt * 64;
        // ---- stage V transposed + combined key ids
        {
            int key = tid & 63;
            int d8  = (tid >> 6) * 8;
            short8 v = *(const short8*)&qkv[(size_t)(b * NN + kb + key) * qrow + 2 * DD + h * HDD + d8];
            #pragma unroll
            for (int e = 0; e < 8; ++e)
                Vt[d8 + e][key] = (unsigned short)v[e];
            if (tid < 64) {
                int kk = b * NN + kb + tid;
                ck[tid] = smask[kk] ? -1 : sids[kk];
            }
        }
        __syncthreads();

        // ---- S = Q K^T : 4 MFMAs over 16-key subtiles
        f32x4 s4[4];
        #pragma unroll
        for (int j = 0; j < 4; ++j) {
            short8 kf = *(const short8*)&qkv[(size_t)(b * NN + kb + 16 * j + c) * qrow + DD + h * HDD + g * 8];
            s4[j] = __builtin_amdgcn_mfma_f32_16x16x32_bf16(qf, kf, zero, 0, 0, 0);
        }

        // ---- mask + scale + per-row tile max
        float pm[4] = {FMIN, FMIN, FMIN, FMIN};
        #pragma unroll
        for (int j = 0; j < 4; ++j) {
            const int ckj = ck[16 * j + c];
            #pragma unroll
            for (int r = 0; r < 4; ++r) {
                float sv = (cq[r] != ckj) ? FMIN : s4[j][r] * scale;
                s4[j][r] = sv;
                pm[r] = fmaxf(pm[r], sv);
            }
        }
        #pragma unroll
        for (int off = 1; off < 16; off <<= 1)
            #pragma unroll
            for (int r = 0; r < 4; ++r)
                pm[r] = fmaxf(pm[r], __shfl_xor(pm[r], off));

        // ---- online update
        float fac[4], psum[4];
        #pragma unroll
        for (int r = 0; r < 4; ++r) {
            float mn = fmaxf(m[r], pm[r]);
            fac[r] = __expf(m[r] - mn);       // -inf - finite -> 0 (first tile)
            m[r] = mn;
            psum[r] = 0.f;
        }
        #pragma unroll
        for (int j = 0; j < 4; ++j) {
            #pragma unroll
            for (int r = 0; r < 4; ++r) {
                float p = __expf(s4[j][r] - m[r]);
                psum[r] += p;
                int row  = 4 * g + r;
                int colb = (2 * (16 * j + c)) ^ ((row & 7) << 4);
                *(unsigned short*)((char*)&P[wave][row][0] + colb) = f2b(p);
            }
        }
        #pragma unroll
        for (int off = 1; off < 16; off <<= 1)
            #pragma unroll
            for (int r = 0; r < 4; ++r)
                psum[r] += __shfl_xor(psum[r], off);
        #pragma unroll
        for (int r = 0; r < 4; ++r) l[r] = l[r] * fac[r] + psum[r];

        #pragma unroll
        for (int dc = 0; dc < 2; ++dc)
            #pragma unroll
            for (int r = 0; r < 4; ++r)
                o[dc][r] *= fac[r];

        // ---- PV: A-frag = P (row=c, k-elems = 8 keys), B-frag = Vt
        #pragma unroll
        for (int kc = 0; kc < 2; ++kc) {
            int colb = (2 * (kc * 32 + g * 8)) ^ ((c & 7) << 4);
            short8 pf = *(const short8*)((char*)&P[wave][c][0] + colb);
            #pragma unroll
            for (int dc = 0; dc < 2; ++dc) {
                short8 vf = *(const short8*)&Vt[dc * 16 + c][kc * 32 + g * 8];
                o[dc] = __builtin_amdgcn_mfma_f32_16x16x32_bf16(pf, vf, o[dc], 0, 0, 0);
            }
        }
        __syncthreads();
    }

    // ---- normalize + write out (bf16 [M][D], heads concatenated)
    #pragma unroll
    for (int r = 0; r < 4; ++r) {
        unsigned short* op = &out[(size_t)(b * NN + q0w + 4 * g + r) * DD + h * HDD];
        if (cq[r] == -2) {                    // fully-masked row: uniform attn
            #pragma unroll
            for (int dc = 0; dc < 2; ++dc)
                op[dc * 16 + c] = vmean[bh * HDD + dc * 16 + c];
        } else {
            const float inv = 1.0f / l[r];
            #pragma unroll
            for (int dc = 0; dc < 2; ++dc)
                op[dc * 16 + c] = f2b(o[dc][r] * inv);
        }
    }
}

// ---------------------------------------------------------------------------
extern "C" void kernel_launch(void* const* d_in, const int* in_sizes, int n_in,
                              void* d_out, int out_size, void* d_ws, size_t ws_size,
                              hipStream_t stream)
{
    const float* x        = (const float*)d_in[0];
    const int*   hids     = (const int*)d_in[1];
    const int*   wids     = (const int*)d_in[2];
    const void*  tmask_rw = d_in[3];
    const int*   sids     = (const int*)d_in[4];
    const void*  smask_rw = d_in[5];
    const float* embed_w  = (const float*)d_in[7];
    const float* embed_b  = (const float*)d_in[8];
    const float* h_embed  = (const float*)d_in[9];
    const float* w_embed  = (const float*)d_in[10];
    const float* mtok     = (const float*)d_in[11];
    const float* norm1_w  = (const float*)d_in[12];
    const float* norm1_b  = (const float*)d_in[13];
    const float* ls1      = (const float*)d_in[14];
    const float* qkv_w    = (const float*)d_in[15];
    const float* qkv_b    = (const float*)d_in[16];
    const float* proj_w   = (const float*)d_in[17];
    const float* proj_b   = (const float*)d_in[18];
    const float* norm2_w  = (const float*)d_in[19];
    const float* norm2_b  = (const float*)d_in[20];
    const float* fc1_w    = (const float*)d_in[21];
    const float* fc1_b    = (const float*)d_in[22];
    const float* fc2_w    = (const float*)d_in[23];
    const float* fc2_b    = (const float*)d_in[24];
    const float* ls2      = (const float*)d_in[25];
    const float* pnorm_w  = (const float*)d_in[26];
    const float* pnorm_b  = (const float*)d_in[27];
    const float* pproj_w  = (const float*)d_in[28];
    const float* pproj_b  = (const float*)d_in[29];

    const size_t MD = (size_t)MM * DD;
    float*          h    = (float*)d_ws;
    unsigned short* zb   = (unsigned short*)(h + MD);
    unsigned short* hid  = zb + MD;                 // 4*MD ushorts
    unsigned short* qkvb = hid;                     // alias (disjoint liveness)
    float*          zf   = (float*)hid;             // alias: pnorm out
    unsigned short* wT   = hid + 4 * MD;
    const size_t qkvTsz  = (size_t)LL * 3 * DD * DD;
    const size_t projTsz = (size_t)LL * DD * DD;
    const size_t fc1Tsz  = (size_t)LL * DD * 4 * DD;
    unsigned short* qkvT = wT;
    unsigned short* projT = qkvT + qkvTsz;
    unsigned short* fc1T  = projT + projTsz;
    unsigned short* fc2T  = fc1T + fc1Tsz;
    int* tm32 = (int*)(fc2T + fc1Tsz);
    int* sm32 = tm32 + MM;
    unsigned short* vmean = (unsigned short*)(sm32 + MM);   // 96*32 bf16
    int2* kmm = (int2*)(vmean + BB * HH * HDD);             // 128 int2
    const size_t ewsz = (size_t)DIN * DD;                   // 294912
    unsigned short* ewT_hi = (unsigned short*)(kmm + BB * 16);
    unsigned short* ewT_lo = ewT_hi + ewsz;
    unsigned short* pwT_hi = ewT_lo + ewsz;
    unsigned short* pwT_lo = pwT_hi + ewsz;

    cvt_mask_k<<<1, 1024, 0, stream>>>(tmask_rw, MM, tm32);
    cvt_mask_k<<<1, 1024, 0, stream>>>(smask_rw, MM, sm32);
    kminmax_k<<<BB * 16, 64, 0, stream>>>(sids, sm32, kmm);

    dim3 t256(256);
    tcast_k<<<dim3(DD/32, 3*DD/32, LL), t256, 0, stream>>>(qkv_w, qkvT, DD, 3*DD);
    tcast_k<<<dim3(DD/32, DD/32,   LL), t256, 0, stream>>>(proj_w, projT, DD, DD);
    tcast_k<<<dim3(DD/32, 4*DD/32, LL), t256, 0, stream>>>(fc1_w, fc1T, DD, 4*DD);
    tcast_k<<<dim3(4*DD/32, DD/32, LL), t256, 0, stream>>>(fc2_w, fc2T, 4*DD, DD);
    tcast2_k<<<dim3(DIN/32, DD/32), t256, 0, stream>>>(embed_w, ewT_hi, ewT_lo, DIN, DD);
    tcast2_k<<<dim3(DD/32, DIN/32), t256, 0, stream>>>(pproj_w, pwT_hi, pwT_lo, DD, DIN);

    // embed + mask_token + pos embeds (bf16x3 split — fp32-comparable precision)
    sgemm_k<1><<<dim3(MM/128, DD/64), t256, 0, stream>>>(
        x, ewT_hi, ewT_lo, embed_b, h, DIN, DD, tm32, hids, wids, mtok, h_embed, w_embed);

    for (int i = 0; i < LL; ++i) {
        ln_k<1><<<MM/4, t256, 0, stream>>>(h, norm1_w + i*DD, norm1_b + i*DD, zb);
        bgemm_k<0><<<dim3(MM/128, 3*DD/128), t256, 0, stream>>>(
            zb, qkvT + (size_t)i*3*DD*DD, qkv_b + i*3*DD, qkvb, DD, 3*DD, nullptr);
        vmean_k<<<BB * HH, t256, 0, stream>>>(qkvb, vmean);
        attn_mfma_k<<<dim3(BB*HH*(NN/64)), t256, 0, stream>>>(
            qkvb, sids, sm32, kmm, vmean, zb);
        bgemm_k<2><<<dim3(MM/128, DD/128), t256, 0, stream>>>(
            zb, projT + (size_t)i*DD*DD, proj_b + i*DD, h, DD, DD, ls1 + i*DD);
        ln_k<1><<<MM/4, t256, 0, stream>>>(h, norm2_w + i*DD, norm2_b + i*DD, zb);
        bgemm_k<3><<<dim3(MM/128, 4*DD/128), t256, 0, stream>>>(
            zb, fc1T + (size_t)i*DD*4*DD, fc1_b + i*4*DD, hid, DD, 4*DD, nullptr);
        bgemm_k<2><<<dim3(MM/128, DD/128), t256, 0, stream>>>(
            hid, fc2T + (size_t)i*4*DD*DD, fc2_b + i*DD, h, 4*DD, DD, ls2 + i*DD);
    }

    ln_k<0><<<MM/4, t256, 0, stream>>>(h, pnorm_w, pnorm_b, zf);
    sgemm_k<0><<<dim3(MM/128, DIN/64), t256, 0, stream>>>(
        zf, pwT_hi, pwT_lo, pproj_b, (float*)d_out, DD, DIN,
        nullptr, nullptr, nullptr, nullptr, nullptr, nullptr);
}